// Round 2
// baseline (959.693 us; speedup 1.0000x reference)
//
#include <hip/hip_runtime.h>
#include <math.h>

#define NN 100000
#define NE 3200000
#define FEA 67
#define HID 16
#define OUTC 2
#define KS 3
#define KH 48   /* KS*HID */
#define KO 6    /* KS*OUTC */
#define NB 98   /* ceil(NN/1024) */
#define NPB 32          /* nodes per bucket */
#define NBUCK 3125      /* NN / NPB (exact) */

// ---------------- degree / scan ----------------

__global__ void k_deg(const int* __restrict__ dst, int* __restrict__ deg) {
    int e = blockIdx.x * 256 + threadIdx.x;
    atomicAdd(&deg[dst[e]], 1);
}

__global__ void k_partial(const int* __restrict__ deg, int* __restrict__ partials) {
    __shared__ int s[256];
    int base = blockIdx.x * 1024;
    int acc = 0;
    for (int i = threadIdx.x; i < 1024; i += 256) {
        int idx = base + i;
        if (idx < NN) acc += deg[idx];
    }
    s[threadIdx.x] = acc;
    __syncthreads();
    for (int off = 128; off > 0; off >>= 1) {
        if (threadIdx.x < off) s[threadIdx.x] += s[threadIdx.x + off];
        __syncthreads();
    }
    if (threadIdx.x == 0) partials[blockIdx.x] = s[0];
}

__global__ void k_scan_partials(int* __restrict__ partials) {
    __shared__ int s[128];
    int t = threadIdx.x;
    int v0 = (t < NB) ? partials[t] : 0;
    s[t] = v0;
    __syncthreads();
    for (int off = 1; off < 128; off <<= 1) {
        int v = (t >= off) ? s[t - off] : 0;
        __syncthreads();
        s[t] += v;
        __syncthreads();
    }
    if (t < NB) partials[t] = s[t] - v0;   // exclusive prefix
}

__global__ void k_downsweep(const int* __restrict__ deg, const int* __restrict__ partials,
                            int* __restrict__ row_start, int* __restrict__ cursor,
                            float* __restrict__ dinv) {
    __shared__ int s[256];
    int base = blockIdx.x * 1024 + threadIdx.x * 4;
    int d0 = 0, d1 = 0, d2 = 0, d3 = 0;
    if (base + 0 < NN) d0 = deg[base + 0];
    if (base + 1 < NN) d1 = deg[base + 1];
    if (base + 2 < NN) d2 = deg[base + 2];
    if (base + 3 < NN) d3 = deg[base + 3];
    int ts = d0 + d1 + d2 + d3;
    s[threadIdx.x] = ts;
    __syncthreads();
    for (int off = 1; off < 256; off <<= 1) {
        int v = (threadIdx.x >= off) ? s[threadIdx.x - off] : 0;
        __syncthreads();
        s[threadIdx.x] += v;
        __syncthreads();
    }
    int excl = s[threadIdx.x] - ts + partials[blockIdx.x];
    int p[4];
    p[0] = excl; p[1] = excl + d0; p[2] = excl + d0 + d1; p[3] = excl + d0 + d1 + d2;
    int dv[4] = {d0, d1, d2, d3};
    #pragma unroll
    for (int q = 0; q < 4; ++q) {
        int idx = base + q;
        if (idx < NN) {
            row_start[idx] = p[q];
            cursor[idx]    = p[q];
            dinv[idx]      = (dv[q] > 0) ? rsqrtf((float)dv[q]) : 0.f;
        }
    }
}

// ---------------- bucketed 2-pass CSR build ----------------

__global__ void k_bcur_init(const int* __restrict__ row_start, int* __restrict__ bcur) {
    int b = blockIdx.x * 256 + threadIdx.x;
    if (b < NBUCK) bcur[b] = row_start[b * NPB];
}

// pass A: append (src,dst) to bucket frontier (bucket = dst>>5); frontier lines fill fully
__global__ void k_passA(const int* __restrict__ src, const int* __restrict__ dst,
                        int* __restrict__ bcur, int2* __restrict__ tmp) {
    int e = blockIdx.x * 256 + threadIdx.x;
    int s = src[e], d = dst[e];
    int pos = atomicAdd(&bcur[d >> 5], 1);
    tmp[pos] = make_int2(s, d);
}

// pass B: scatter within 8KB bucket region (L2-resident), fuse norm weight
__global__ void k_passB(const int2* __restrict__ tmp, const float* __restrict__ dinv,
                        int* __restrict__ cursor, int2* __restrict__ csr) {
    int e = blockIdx.x * 256 + threadIdx.x;
    int2 c = tmp[e];
    float w = dinv[c.x] * dinv[c.y];
    int pos = atomicAdd(&cursor[c.y], 1);
    csr[pos] = make_int2(c.x, __float_as_int(w));
}

// ---------------- layer 1 dense transform ----------------

__global__ void k_transform1(const float* __restrict__ x, const float* __restrict__ iw,
                             const float* __restrict__ rw, const float* __restrict__ b1,
                             float* __restrict__ A, float* __restrict__ R) {
    __shared__ float xs[16 * FEA];
    __shared__ float w0[KS * FEA * HID];
    __shared__ float wr[KS * FEA * HID];
    __shared__ float bb[KH];
    int n0 = blockIdx.x * 16;
    for (int i = threadIdx.x; i < KS * FEA * HID; i += 256) { w0[i] = iw[i]; wr[i] = rw[i]; }
    if (threadIdx.x < KH) bb[threadIdx.x] = b1[threadIdx.x];
    for (int i = threadIdx.x; i < 16 * FEA; i += 256) xs[i] = x[n0 * FEA + i];
    __syncthreads();
    for (int it = threadIdx.x; it < 16 * KH; it += 256) {
        int nl = it / KH, j = it % KH;
        int k = j >> 4, hh = j & 15;
        float a0 = 0.f, aR = bb[j];
        const float* wp0 = &w0[k * FEA * HID + hh];
        const float* wpr = &wr[k * FEA * HID + hh];
        const float* xp  = &xs[nl * FEA];
        #pragma unroll
        for (int f = 0; f < FEA; ++f) {
            float xv = xp[f];
            a0 += xv * wp0[f * HID];
            aR += xv * wpr[f * HID];
        }
        int n = n0 + nl;
        A[n * KH + j] = a0;
        R[n * KH + j] = aR;
    }
}

// ---------------- SpMM 48-wide (wave per node), optional fused 16x16 gemm ----------------

template <bool FUSEW>
__global__ void k_spmm48(const float* __restrict__ Asrc, const float* __restrict__ R,
                         const int* __restrict__ row_start, const int* __restrict__ deg,
                         const int2* __restrict__ csr, const float* __restrict__ w1,
                         float* __restrict__ Bout) {
    __shared__ float w1s[FUSEW ? KS * HID * HID : 1];
    if (FUSEW) {
        for (int i = threadIdx.x; i < KS * HID * HID; i += 256) w1s[i] = w1[i];
        __syncthreads();
    }
    int node = (blockIdx.x * 256 + threadIdx.x) >> 6;   // one wave per node
    int lane = threadIdx.x & 63;
    if (lane >= KH) return;
    int start = __builtin_amdgcn_readfirstlane(row_start[node]);
    int d     = __builtin_amdgcn_readfirstlane(deg[node]);
    float acc = R[node * KH + lane];
    int e = 0;
    for (; e + 4 <= d; e += 4) {
        int2 c0 = csr[start + e + 0];
        int2 c1 = csr[start + e + 1];
        int2 c2 = csr[start + e + 2];
        int2 c3 = csr[start + e + 3];
        float a0 = Asrc[c0.x * KH + lane];
        float a1 = Asrc[c1.x * KH + lane];
        float a2 = Asrc[c2.x * KH + lane];
        float a3 = Asrc[c3.x * KH + lane];
        acc += __int_as_float(c0.y) * a0;
        acc += __int_as_float(c1.y) * a1;
        acc += __int_as_float(c2.y) * a2;
        acc += __int_as_float(c3.y) * a3;
    }
    for (; e < d; ++e) {
        int2 c = csr[start + e];
        acc += __int_as_float(c.y) * Asrc[c.x * KH + lane];
    }
    acc = fmaxf(acc, 0.f);   // both layer-1 propagates end in relu
    if (FUSEW) {
        // A'[n, k*16+p] = sum_h relu_out[n, k*16+h] * w1[k][h][p]
        int k = lane >> 4, p = lane & 15, k16 = k << 4;
        float a2s = 0.f;
        #pragma unroll
        for (int h = 0; h < HID; ++h)
            a2s += __shfl(acc, k16 + h, 64) * w1s[k * 256 + h * 16 + p];
        Bout[node * KH + lane] = a2s;
    } else {
        Bout[node * KH + lane] = acc;
    }
}

// ---------------- fused mean+relu+transform2 ----------------

__global__ void k_mt2(const float* __restrict__ L1, const float* __restrict__ iw,
                      const float* __restrict__ rw, const float* __restrict__ b2,
                      float* __restrict__ A2, float* __restrict__ R2) {
    __shared__ float wi[KS * HID * OUTC];
    __shared__ float wr_[KS * HID * OUTC];
    __shared__ float bb[KO];
    if (threadIdx.x < KS * HID * OUTC) { wi[threadIdx.x] = iw[threadIdx.x]; wr_[threadIdx.x] = rw[threadIdx.x]; }
    if (threadIdx.x < KO) bb[threadIdx.x] = b2[threadIdx.x];
    __syncthreads();
    int n = blockIdx.x * 256 + threadIdx.x;
    if (n >= NN) return;
    const float4* ap = (const float4*)(L1 + (size_t)n * KH);
    float v[KH];
    #pragma unroll
    for (int q = 0; q < 12; ++q) {
        float4 t = ap[q];
        v[q * 4 + 0] = t.x; v[q * 4 + 1] = t.y; v[q * 4 + 2] = t.z; v[q * 4 + 3] = t.w;
    }
    float h[HID];
    #pragma unroll
    for (int hh = 0; hh < HID; ++hh)
        h[hh] = fmaxf((v[hh] + v[16 + hh] + v[32 + hh]) * (1.f / 3.f), 0.f);
    #pragma unroll
    for (int k = 0; k < KS; ++k) {
        #pragma unroll
        for (int o = 0; o < OUTC; ++o) {
            float a = 0.f, r = bb[k * 2 + o];
            #pragma unroll
            for (int hh = 0; hh < HID; ++hh) {
                a += h[hh] * wi[k * 32 + hh * 2 + o];
                r += h[hh] * wr_[k * 32 + hh * 2 + o];
            }
            A2[n * KO + k * 2 + o] = a;
            R2[n * KO + k * 2 + o] = r;
        }
    }
}

// ---------------- SpMM 6-wide #1: fused 2x2 gemm (w2) ----------------

__global__ void k_spmm6_g(const float* __restrict__ Asrc, const float* __restrict__ R2,
                          const int* __restrict__ row_start, const int* __restrict__ deg,
                          const int2* __restrict__ csr, const float* __restrict__ w2,
                          float* __restrict__ Bout) {
    __shared__ float ws[KS * OUTC * OUTC];
    if (threadIdx.x < KS * OUTC * OUTC) ws[threadIdx.x] = w2[threadIdx.x];
    __syncthreads();
    int t = blockIdx.x * 256 + threadIdx.x;
    int node = t / KO, j = t % KO;
    bool active = node < NN;
    float acc = 0.f;
    int start = 0, d = 0;
    if (active) {
        start = row_start[node];
        d     = deg[node];
        acc   = R2[node * KO + j];
    }
    int e = 0;
    for (; e + 4 <= d; e += 4) {
        int2 c0 = csr[start + e + 0];
        int2 c1 = csr[start + e + 1];
        int2 c2 = csr[start + e + 2];
        int2 c3 = csr[start + e + 3];
        acc += __int_as_float(c0.y) * Asrc[c0.x * KO + j];
        acc += __int_as_float(c1.y) * Asrc[c1.x * KO + j];
        acc += __int_as_float(c2.y) * Asrc[c2.x * KO + j];
        acc += __int_as_float(c3.y) * Asrc[c3.x * KO + j];
    }
    for (; e < d; ++e) {
        int2 c = csr[start + e];
        acc += __int_as_float(c.y) * Asrc[c.x * KO + j];
    }
    // fused: out[k,p] = v[k,0]*w2[k,0,p] + v[k,1]*w2[k,1,p]; partner lane = t^1
    float other = __shfl_xor(acc, 1, 64);
    if (active) {
        int k = j >> 1, p = j & 1;
        float v0 = (p == 0) ? acc : other;
        float v1 = (p == 0) ? other : acc;
        Bout[node * KO + j] = v0 * ws[k * 4 + p] + v1 * ws[k * 4 + 2 + p];
    }
}

// ---------------- SpMM 6-wide #2: fused mean + log_softmax (10 nodes/wave) ----------------

__global__ void k_spmm6_f(const float* __restrict__ Asrc, const float* __restrict__ R2,
                          const int* __restrict__ row_start, const int* __restrict__ deg,
                          const int2* __restrict__ csr, float* __restrict__ out) {
    int wave = threadIdx.x >> 6;
    int l    = threadIdx.x & 63;
    int nl   = l / 6;            // 0..10 (10 = inactive)
    int j    = l - nl * 6;
    bool active = nl < 10;
    int node = blockIdx.x * 40 + wave * 10 + nl;   // grid exact: NN/40 blocks
    float acc = 0.f;
    int start = 0, d = 0;
    if (active) {
        start = row_start[node];
        d     = deg[node];
        acc   = R2[node * KO + j];
    }
    int e = 0;
    for (; e + 4 <= d; e += 4) {
        int2 c0 = csr[start + e + 0];
        int2 c1 = csr[start + e + 1];
        int2 c2 = csr[start + e + 2];
        int2 c3 = csr[start + e + 3];
        acc += __int_as_float(c0.y) * Asrc[c0.x * KO + j];
        acc += __int_as_float(c1.y) * Asrc[c1.x * KO + j];
        acc += __int_as_float(c2.y) * Asrc[c2.x * KO + j];
        acc += __int_as_float(c3.y) * Asrc[c3.x * KO + j];
    }
    for (; e < d; ++e) {
        int2 c = csr[start + e];
        acc += __int_as_float(c.y) * Asrc[c.x * KO + j];
    }
    int base = nl * 6;
    float o0 = (__shfl(acc, base + 0, 64) + __shfl(acc, base + 2, 64) + __shfl(acc, base + 4, 64)) * (1.f / 3.f);
    float o1 = (__shfl(acc, base + 1, 64) + __shfl(acc, base + 3, 64) + __shfl(acc, base + 5, 64)) * (1.f / 3.f);
    if (active && j == 0) {
        float m = fmaxf(o0, o1);
        float ls = m + logf(expf(o0 - m) + expf(o1 - m));
        *(float2*)(out + (size_t)node * 2) = make_float2(o0 - ls, o1 - ls);
    }
}

// ---------------- host ----------------

extern "C" void kernel_launch(void* const* d_in, const int* in_sizes, int n_in,
                              void* d_out, int out_size, void* d_ws, size_t ws_size,
                              hipStream_t stream) {
    const float* x   = (const float*)d_in[0];
    const int*   ei  = (const int*)d_in[1];
    const float* iw1 = (const float*)d_in[2];
    const float* w1  = (const float*)d_in[3];
    const float* rw1 = (const float*)d_in[4];
    const float* b1  = (const float*)d_in[5];
    const float* iw2 = (const float*)d_in[6];
    const float* w2  = (const float*)d_in[7];
    const float* rw2 = (const float*)d_in[8];
    const float* b2  = (const float*)d_in[9];
    const int* src = ei;
    const int* dst = ei + NE;
    float* out = (float*)d_out;

    char* ws = (char*)d_ws;
    size_t o = 0;
    int*   deg       = (int*)(ws + o);   o += (size_t)NN * 4;
    int*   row_start = (int*)(ws + o);   o += (size_t)NN * 4;
    int*   cursor    = (int*)(ws + o);   o += (size_t)NN * 4;
    float* dinv      = (float*)(ws + o); o += (size_t)NN * 4;
    int*   bcur      = (int*)(ws + o);   o += 3136 * 4;
    int*   partials  = (int*)(ws + o);   o += 128 * 4;
    int2*  csr       = (int2*)(ws + o);  o += (size_t)NE * 8;
    float* A         = (float*)(ws + o); o += (size_t)NN * KH * 4;
    float* R         = (float*)(ws + o); o += (size_t)NN * KH * 4;
    float* B         = (float*)(ws + o); o += (size_t)NN * KH * 4;
    // overlays
    int2*  tmp = (int2*)A;                    // NE*8 = 25.6MB <= A+R (38.4MB); dead before transform1
    float* A2  = R;                           // layer-2 buffers live in R (free after 2nd spmm48)
    float* R2  = R + (size_t)NN * KO;
    float* C2  = R + (size_t)NN * KO * 2;

    hipMemsetAsync(deg, 0, (size_t)NN * 4, stream);
    k_deg          <<<NE / 256, 256, 0, stream>>>(dst, deg);
    k_partial      <<<NB, 256, 0, stream>>>(deg, partials);
    k_scan_partials<<<1, 128, 0, stream>>>(partials);
    k_downsweep    <<<NB, 256, 0, stream>>>(deg, partials, row_start, cursor, dinv);
    k_bcur_init    <<<(NBUCK + 255) / 256, 256, 0, stream>>>(row_start, bcur);
    k_passA        <<<NE / 256, 256, 0, stream>>>(src, dst, bcur, tmp);
    k_passB        <<<NE / 256, 256, 0, stream>>>(tmp, dinv, cursor, csr);

    // layer 1
    k_transform1   <<<NN / 16, 256, 0, stream>>>(x, iw1, rw1, b1, A, R);
    k_spmm48<true> <<<NN / 4, 256, 0, stream>>>(A, R, row_start, deg, csr, w1, B);   // + fused gemm16
    k_spmm48<false><<<NN / 4, 256, 0, stream>>>(B, R, row_start, deg, csr, w1, A);

    // layer 2
    k_mt2          <<<(NN + 255) / 256, 256, 0, stream>>>(A, iw2, rw2, b2, A2, R2);
    k_spmm6_g      <<<(NN * KO + 255) / 256, 256, 0, stream>>>(A2, R2, row_start, deg, csr, w2, C2);
    k_spmm6_f      <<<NN / 40, 256, 0, stream>>>(C2, R2, row_start, deg, csr, out);
}

// Round 3
// 428.451 us; speedup vs baseline: 2.2399x; 2.2399x over previous
//
#include <hip/hip_runtime.h>
#include <math.h>

#define NN 100000
#define NE 3200000
#define FEA 67
#define HID 16
#define OUTC 2
#define KS 3
#define KH 48   /* KS*HID */
#define KO 6    /* KS*OUTC */

#define PB 512          /* partition blocks */
#define EPB 6250        /* edges per partition block (PB*EPB == NE) */
#define BINW 512        /* nodes per bin */
#define NBINS 196       /* ceil(NN/BINW) */
#define M1 (NBINS * PB) /* 100352 */
#define NSCB 98         /* scan blocks: 98*1024 >= max(M1, NN); M1 = 98*1024 exactly */

// ---------------- partition: histogram ----------------

__global__ void k_hist(const int* __restrict__ dst, int* __restrict__ hist) {
    __shared__ int h[NBINS];
    if (threadIdx.x < NBINS) h[threadIdx.x] = 0;
    __syncthreads();
    int base = blockIdx.x * EPB;
    for (int i = threadIdx.x; i < EPB; i += 256)
        atomicAdd(&h[dst[base + i] >> 9], 1);
    __syncthreads();
    if (threadIdx.x < NBINS) hist[threadIdx.x * PB + blockIdx.x] = h[threadIdx.x];
}

// ---------------- generic 3-kernel exclusive scan ----------------

__global__ void k_partial(const int* __restrict__ in, int* __restrict__ partials, int n) {
    __shared__ int s[256];
    int base = blockIdx.x * 1024;
    int acc = 0;
    for (int i = threadIdx.x; i < 1024; i += 256) {
        int idx = base + i;
        if (idx < n) acc += in[idx];
    }
    s[threadIdx.x] = acc;
    __syncthreads();
    for (int off = 128; off > 0; off >>= 1) {
        if (threadIdx.x < off) s[threadIdx.x] += s[threadIdx.x + off];
        __syncthreads();
    }
    if (threadIdx.x == 0) partials[blockIdx.x] = s[0];
}

__global__ void k_scan_partials(int* __restrict__ partials, int nb) {
    __shared__ int s[128];
    int t = threadIdx.x;
    int v0 = (t < nb) ? partials[t] : 0;
    s[t] = v0;
    __syncthreads();
    for (int off = 1; off < 128; off <<= 1) {
        int v = (t >= off) ? s[t - off] : 0;
        __syncthreads();
        s[t] += v;
        __syncthreads();
    }
    if (t < nb) partials[t] = s[t] - v0;   // exclusive prefix of block sums
}

__global__ void k_downsweep(const int* __restrict__ in, const int* __restrict__ partials,
                            int* __restrict__ out, int n) {
    __shared__ int s[256];
    int base = blockIdx.x * 1024 + threadIdx.x * 4;
    int d0 = 0, d1 = 0, d2 = 0, d3 = 0;
    if (base + 0 < n) d0 = in[base + 0];
    if (base + 1 < n) d1 = in[base + 1];
    if (base + 2 < n) d2 = in[base + 2];
    if (base + 3 < n) d3 = in[base + 3];
    int ts = d0 + d1 + d2 + d3;
    s[threadIdx.x] = ts;
    __syncthreads();
    for (int off = 1; off < 256; off <<= 1) {
        int v = (threadIdx.x >= off) ? s[threadIdx.x - off] : 0;
        __syncthreads();
        s[threadIdx.x] += v;
        __syncthreads();
    }
    int excl = s[threadIdx.x] - ts + partials[blockIdx.x];
    int p0 = excl, p1 = excl + d0, p2 = excl + d0 + d1, p3 = excl + d0 + d1 + d2;
    if (base + 0 < n) out[base + 0] = p0;
    if (base + 1 < n) out[base + 1] = p1;
    if (base + 2 < n) out[base + 2] = p2;
    if (base + 3 < n) out[base + 3] = p3;
}

// ---------------- partition: scatter to bins (pre-scanned, no global atomics) ----------------

__global__ void k_pass2(const int* __restrict__ src, const int* __restrict__ dst,
                        const int* __restrict__ hist_scan, int* __restrict__ recs) {
    __shared__ int curs[NBINS];
    if (threadIdx.x < NBINS) curs[threadIdx.x] = hist_scan[threadIdx.x * PB + blockIdx.x];
    __syncthreads();
    int base = blockIdx.x * EPB;
    for (int i = threadIdx.x; i < EPB; i += 256) {
        int e = base + i;
        int s = src[e], d = dst[e];
        int pos = atomicAdd(&curs[d >> 9], 1);        // LDS atomic, private run
        recs[pos] = s | ((d & 511) << 17);            // src:17b | dst_local:9b
    }
}

// ---------------- per-bin degree + dinv (replaces global-atomic k_deg) ----------------

__global__ void k_deghist(const int* __restrict__ recs, const int* __restrict__ hist_scan,
                          int* __restrict__ deg, float* __restrict__ dinv) {
    __shared__ int cnt[BINW];
    int bin = blockIdx.x;
    cnt[threadIdx.x] = 0;
    __syncthreads();
    int s0 = hist_scan[bin * PB];
    int s1 = (bin + 1 < NBINS) ? hist_scan[(bin + 1) * PB] : NE;
    for (int r = s0 + threadIdx.x; r < s1; r += BINW)
        atomicAdd(&cnt[recs[r] >> 17], 1);
    __syncthreads();
    int node = bin * BINW + threadIdx.x;
    if (node < NN) {
        int c = cnt[threadIdx.x];
        deg[node]  = c;
        dinv[node] = (c > 0) ? rsqrtf((float)c) : 0.f;
    }
}

// ---------------- per-bin CSR scatter (L2-local region) ----------------

__global__ void k_binsort(const int* __restrict__ recs, const int* __restrict__ hist_scan,
                          const int* __restrict__ row_start, int* __restrict__ csr) {
    __shared__ int curs[BINW];
    int bin = blockIdx.x;
    int node = bin * BINW + threadIdx.x;
    curs[threadIdx.x] = (node < NN) ? row_start[node] : 0;
    __syncthreads();
    int s0 = hist_scan[bin * PB];
    int s1 = (bin + 1 < NBINS) ? hist_scan[(bin + 1) * PB] : NE;
    for (int r = s0 + threadIdx.x; r < s1; r += BINW) {
        int rec = recs[r];
        int pos = atomicAdd(&curs[rec >> 17], 1);
        csr[pos] = rec & 0x1FFFF;                     // src only; weights factorized out
    }
}

// ---------------- layer 1 dense transform (A pre-scaled by dinv) ----------------

__global__ void k_transform1(const float* __restrict__ x, const float* __restrict__ iw,
                             const float* __restrict__ rw, const float* __restrict__ b1,
                             const float* __restrict__ dinv,
                             float* __restrict__ A, float* __restrict__ R) {
    __shared__ float xs[16 * FEA];
    __shared__ float w0[KS * FEA * HID];
    __shared__ float wr[KS * FEA * HID];
    __shared__ float bb[KH];
    int n0 = blockIdx.x * 16;
    for (int i = threadIdx.x; i < KS * FEA * HID; i += 256) { w0[i] = iw[i]; wr[i] = rw[i]; }
    if (threadIdx.x < KH) bb[threadIdx.x] = b1[threadIdx.x];
    for (int i = threadIdx.x; i < 16 * FEA; i += 256) xs[i] = x[n0 * FEA + i];
    __syncthreads();
    for (int it = threadIdx.x; it < 16 * KH; it += 256) {
        int nl = it / KH, j = it % KH;
        int k = j >> 4, hh = j & 15;
        float a0 = 0.f, aR = bb[j];
        const float* wp0 = &w0[k * FEA * HID + hh];
        const float* wpr = &wr[k * FEA * HID + hh];
        const float* xp  = &xs[nl * FEA];
        #pragma unroll
        for (int f = 0; f < FEA; ++f) {
            float xv = xp[f];
            a0 += xv * wp0[f * HID];
            aR += xv * wpr[f * HID];
        }
        int n = n0 + nl;
        A[n * KH + j] = a0 * dinv[n];
        R[n * KH + j] = aR;
    }
}

// ---------------- SpMM 48-wide (wave per node), optional fused 16x16 gemm ----------------

template <bool FUSEW>
__global__ void k_spmm48(const float* __restrict__ Asrc, const float* __restrict__ R,
                         const int* __restrict__ row_start, const int* __restrict__ deg,
                         const float* __restrict__ dinv, const int* __restrict__ csr,
                         const float* __restrict__ w1, float* __restrict__ Bout) {
    __shared__ float w1s[FUSEW ? KS * HID * HID : 1];
    if (FUSEW) {
        for (int i = threadIdx.x; i < KS * HID * HID; i += 256) w1s[i] = w1[i];
        __syncthreads();
    }
    int node = (blockIdx.x * 256 + threadIdx.x) >> 6;   // one wave per node
    int lane = threadIdx.x & 63;
    if (lane >= KH) return;
    int start = __builtin_amdgcn_readfirstlane(row_start[node]);
    int d     = __builtin_amdgcn_readfirstlane(deg[node]);
    float r   = R[node * KH + lane];
    float dv  = dinv[node];
    float acc = 0.f;
    int e = 0;
    for (; e + 4 <= d; e += 4) {
        int c0 = csr[start + e + 0];
        int c1 = csr[start + e + 1];
        int c2 = csr[start + e + 2];
        int c3 = csr[start + e + 3];
        acc += Asrc[c0 * KH + lane];
        acc += Asrc[c1 * KH + lane];
        acc += Asrc[c2 * KH + lane];
        acc += Asrc[c3 * KH + lane];
    }
    for (; e < d; ++e)
        acc += Asrc[csr[start + e] * KH + lane];
    acc = fmaxf(acc * dv + r, 0.f);   // post-scale dinv[dst]; both layer-1 steps relu
    if (FUSEW) {
        // A'[n, k*16+p] = (sum_h relu_out[n, k*16+h] * w1[k][h][p]) * dinv[n]
        int k = lane >> 4, p = lane & 15, k16 = k << 4;
        float a2s = 0.f;
        #pragma unroll
        for (int h = 0; h < HID; ++h)
            a2s += __shfl(acc, k16 + h, 64) * w1s[k * 256 + h * 16 + p];
        Bout[node * KH + lane] = a2s * dv;
    } else {
        Bout[node * KH + lane] = acc;
    }
}

// ---------------- fused mean+relu+transform2 (A2 pre-scaled by dinv) ----------------

__global__ void k_mt2(const float* __restrict__ L1, const float* __restrict__ iw,
                      const float* __restrict__ rw, const float* __restrict__ b2,
                      const float* __restrict__ dinv,
                      float* __restrict__ A2, float* __restrict__ R2) {
    __shared__ float wi[KS * HID * OUTC];
    __shared__ float wr_[KS * HID * OUTC];
    __shared__ float bb[KO];
    if (threadIdx.x < KS * HID * OUTC) { wi[threadIdx.x] = iw[threadIdx.x]; wr_[threadIdx.x] = rw[threadIdx.x]; }
    if (threadIdx.x < KO) bb[threadIdx.x] = b2[threadIdx.x];
    __syncthreads();
    int n = blockIdx.x * 256 + threadIdx.x;
    if (n >= NN) return;
    const float4* ap = (const float4*)(L1 + (size_t)n * KH);
    float v[KH];
    #pragma unroll
    for (int q = 0; q < 12; ++q) {
        float4 t = ap[q];
        v[q * 4 + 0] = t.x; v[q * 4 + 1] = t.y; v[q * 4 + 2] = t.z; v[q * 4 + 3] = t.w;
    }
    float h[HID];
    #pragma unroll
    for (int hh = 0; hh < HID; ++hh)
        h[hh] = fmaxf((v[hh] + v[16 + hh] + v[32 + hh]) * (1.f / 3.f), 0.f);
    float dv = dinv[n];
    #pragma unroll
    for (int k = 0; k < KS; ++k) {
        #pragma unroll
        for (int o = 0; o < OUTC; ++o) {
            float a = 0.f, r = bb[k * 2 + o];
            #pragma unroll
            for (int hh = 0; hh < HID; ++hh) {
                a += h[hh] * wi[k * 32 + hh * 2 + o];
                r += h[hh] * wr_[k * 32 + hh * 2 + o];
            }
            A2[n * KO + k * 2 + o] = a * dv;
            R2[n * KO + k * 2 + o] = r;
        }
    }
}

// ---------------- SpMM 6-wide #1: fused 2x2 gemm (w2), output pre-scaled ----------------

__global__ void k_spmm6_g(const float* __restrict__ Asrc, const float* __restrict__ R2,
                          const int* __restrict__ row_start, const int* __restrict__ deg,
                          const float* __restrict__ dinv, const int* __restrict__ csr,
                          const float* __restrict__ w2, float* __restrict__ Bout) {
    __shared__ float ws[KS * OUTC * OUTC];
    if (threadIdx.x < KS * OUTC * OUTC) ws[threadIdx.x] = w2[threadIdx.x];
    __syncthreads();
    int t = blockIdx.x * 256 + threadIdx.x;
    int node = t / KO, j = t % KO;
    bool active = node < NN;
    float acc = 0.f, r = 0.f, dv = 0.f;
    int start = 0, d = 0;
    if (active) {
        start = row_start[node];
        d     = deg[node];
        r     = R2[node * KO + j];
        dv    = dinv[node];
    }
    int e = 0;
    for (; e + 4 <= d; e += 4) {
        int c0 = csr[start + e + 0];
        int c1 = csr[start + e + 1];
        int c2 = csr[start + e + 2];
        int c3 = csr[start + e + 3];
        acc += Asrc[c0 * KO + j];
        acc += Asrc[c1 * KO + j];
        acc += Asrc[c2 * KO + j];
        acc += Asrc[c3 * KO + j];
    }
    for (; e < d; ++e)
        acc += Asrc[csr[start + e] * KO + j];
    float v = acc * dv + r;
    float other = __shfl_xor(v, 1, 64);
    if (active) {
        int k = j >> 1, p = j & 1;
        float v0 = (p == 0) ? v : other;
        float v1 = (p == 0) ? other : v;
        Bout[node * KO + j] = (v0 * ws[k * 4 + p] + v1 * ws[k * 4 + 2 + p]) * dv;
    }
}

// ---------------- SpMM 6-wide #2: fused mean + log_softmax (10 nodes/wave) ----------------

__global__ void k_spmm6_f(const float* __restrict__ Asrc, const float* __restrict__ R2,
                          const int* __restrict__ row_start, const int* __restrict__ deg,
                          const float* __restrict__ dinv, const int* __restrict__ csr,
                          float* __restrict__ out) {
    int wave = threadIdx.x >> 6;
    int l    = threadIdx.x & 63;
    int nl   = l / 6;            // 0..10 (10 = inactive)
    int j    = l - nl * 6;
    bool active = nl < 10;
    int node = blockIdx.x * 40 + wave * 10 + nl;
    float acc = 0.f, r = 0.f, dv = 0.f;
    int start = 0, d = 0;
    if (active) {
        start = row_start[node];
        d     = deg[node];
        r     = R2[node * KO + j];
        dv    = dinv[node];
    }
    int e = 0;
    for (; e + 4 <= d; e += 4) {
        int c0 = csr[start + e + 0];
        int c1 = csr[start + e + 1];
        int c2 = csr[start + e + 2];
        int c3 = csr[start + e + 3];
        acc += Asrc[c0 * KO + j];
        acc += Asrc[c1 * KO + j];
        acc += Asrc[c2 * KO + j];
        acc += Asrc[c3 * KO + j];
    }
    for (; e < d; ++e)
        acc += Asrc[csr[start + e] * KO + j];
    float v = acc * dv + r;
    int base = nl * 6;
    float o0 = (__shfl(v, base + 0, 64) + __shfl(v, base + 2, 64) + __shfl(v, base + 4, 64)) * (1.f / 3.f);
    float o1 = (__shfl(v, base + 1, 64) + __shfl(v, base + 3, 64) + __shfl(v, base + 5, 64)) * (1.f / 3.f);
    if (active && j == 0) {
        float m = fmaxf(o0, o1);
        float ls = m + logf(expf(o0 - m) + expf(o1 - m));
        *(float2*)(out + (size_t)node * 2) = make_float2(o0 - ls, o1 - ls);
    }
}

// ---------------- host ----------------

extern "C" void kernel_launch(void* const* d_in, const int* in_sizes, int n_in,
                              void* d_out, int out_size, void* d_ws, size_t ws_size,
                              hipStream_t stream) {
    const float* x   = (const float*)d_in[0];
    const int*   ei  = (const int*)d_in[1];
    const float* iw1 = (const float*)d_in[2];
    const float* w1  = (const float*)d_in[3];
    const float* rw1 = (const float*)d_in[4];
    const float* b1  = (const float*)d_in[5];
    const float* iw2 = (const float*)d_in[6];
    const float* w2  = (const float*)d_in[7];
    const float* rw2 = (const float*)d_in[8];
    const float* b2  = (const float*)d_in[9];
    const int* src = ei;
    const int* dst = ei + NE;
    float* out = (float*)d_out;

    char* ws = (char*)d_ws;
    size_t o = 0;
    int*   deg       = (int*)(ws + o);   o += (size_t)NN * 4;
    int*   row_start = (int*)(ws + o);   o += (size_t)NN * 4;
    float* dinv      = (float*)(ws + o); o += (size_t)NN * 4;
    int*   hist      = (int*)(ws + o);   o += (size_t)M1 * 4;
    int*   hist_scan = (int*)(ws + o);   o += (size_t)M1 * 4;
    int*   partials  = (int*)(ws + o);   o += 128 * 4;
    int*   csr       = (int*)(ws + o);   o += (size_t)NE * 4;        // 12.8MB (src only)
    float* A         = (float*)(ws + o); o += (size_t)NN * KH * 4;   // 19.2MB
    float* R         = (float*)(ws + o); o += (size_t)NN * KH * 4;
    float* B         = (float*)(ws + o); o += (size_t)NN * KH * 4;
    // overlays
    int*   recs = (int*)B;                  // 12.8MB, dead before spmm48 writes B
    float* A2   = R;                        // layer-2 buffers live in R
    float* R2   = R + (size_t)NN * KO;
    float* C2   = R + (size_t)NN * KO * 2;

    // ---- CSR build: hist -> scan -> scatter -> deg -> scan -> bin-local sort ----
    k_hist          <<<PB, 256, 0, stream>>>(dst, hist);
    k_partial       <<<NSCB, 256, 0, stream>>>(hist, partials, M1);
    k_scan_partials <<<1, 128, 0, stream>>>(partials, NSCB);
    k_downsweep     <<<NSCB, 256, 0, stream>>>(hist, partials, hist_scan, M1);
    k_pass2         <<<PB, 256, 0, stream>>>(src, dst, hist_scan, recs);
    k_deghist       <<<NBINS, BINW, 0, stream>>>(recs, hist_scan, deg, dinv);
    k_partial       <<<NSCB, 256, 0, stream>>>(deg, partials, NN);
    k_scan_partials <<<1, 128, 0, stream>>>(partials, NSCB);
    k_downsweep     <<<NSCB, 256, 0, stream>>>(deg, partials, row_start, NN);
    k_binsort       <<<NBINS, BINW, 0, stream>>>(recs, hist_scan, row_start, csr);

    // ---- layer 1 ----
    k_transform1    <<<NN / 16, 256, 0, stream>>>(x, iw1, rw1, b1, dinv, A, R);
    k_spmm48<true>  <<<NN / 4, 256, 0, stream>>>(A, R, row_start, deg, dinv, csr, w1, B);
    k_spmm48<false> <<<NN / 4, 256, 0, stream>>>(B, R, row_start, deg, dinv, csr, w1, A);

    // ---- layer 2 ----
    k_mt2           <<<(NN + 255) / 256, 256, 0, stream>>>(A, iw2, rw2, b2, dinv, A2, R2);
    k_spmm6_g       <<<(NN * KO + 255) / 256, 256, 0, stream>>>(A2, R2, row_start, deg, dinv, csr, w2, C2);
    k_spmm6_f       <<<NN / 40, 256, 0, stream>>>(C2, R2, row_start, deg, dinv, csr, out);
}

// Round 4
// 376.114 us; speedup vs baseline: 2.5516x; 1.1392x over previous
//
#include <hip/hip_runtime.h>
#include <hip/hip_fp16.h>
#include <math.h>

#define NN 100000
#define NE 3200000
#define FEA 67
#define HID 16
#define OUTC 2
#define KS 3
#define KH 48   /* KS*HID */
#define KO 6    /* KS*OUTC */

#define PB 512          /* partition blocks */
#define EPB 6250        /* edges per partition block (PB*EPB == NE) */
#define BINW 512        /* nodes per bin */
#define NBINS 196       /* ceil(NN/BINW) */
#define M1 (NBINS * PB) /* 100352 */
#define NSCB 98         /* scan blocks: 98*1024 == M1 exactly */

// ---------------- partition: histogram ----------------

__global__ void k_hist(const int* __restrict__ dst, int* __restrict__ hist) {
    __shared__ int h[NBINS];
    if (threadIdx.x < NBINS) h[threadIdx.x] = 0;
    __syncthreads();
    int base = blockIdx.x * EPB;
    for (int i = threadIdx.x; i < EPB; i += 256)
        atomicAdd(&h[dst[base + i] >> 9], 1);
    __syncthreads();
    if (threadIdx.x < NBINS) hist[threadIdx.x * PB + blockIdx.x] = h[threadIdx.x];
}

// ---------------- 2-kernel exclusive scan (scan-of-partials fused into downsweep) ----------------

__global__ void k_partial(const int* __restrict__ in, int* __restrict__ partials, int n) {
    __shared__ int s[256];
    int base = blockIdx.x * 1024;
    int acc = 0;
    for (int i = threadIdx.x; i < 1024; i += 256) {
        int idx = base + i;
        if (idx < n) acc += in[idx];
    }
    s[threadIdx.x] = acc;
    __syncthreads();
    for (int off = 128; off > 0; off >>= 1) {
        if (threadIdx.x < off) s[threadIdx.x] += s[threadIdx.x + off];
        __syncthreads();
    }
    if (threadIdx.x == 0) partials[blockIdx.x] = s[0];
}

__global__ void k_downsweepF(const int* __restrict__ in, const int* __restrict__ partials,
                             int* __restrict__ out, int n) {
    __shared__ int ps[256];
    __shared__ int s[256];
    int t = threadIdx.x;
    ps[t] = (t < NSCB) ? partials[t] : 0;
    __syncthreads();
    for (int off = 1; off < 256; off <<= 1) {
        int v = (t >= off) ? ps[t - off] : 0;
        __syncthreads();
        ps[t] += v;
        __syncthreads();
    }
    int bbase = (blockIdx.x > 0) ? ps[blockIdx.x - 1] : 0;

    int base = blockIdx.x * 1024 + t * 4;
    int d0 = 0, d1 = 0, d2 = 0, d3 = 0;
    if (base + 0 < n) d0 = in[base + 0];
    if (base + 1 < n) d1 = in[base + 1];
    if (base + 2 < n) d2 = in[base + 2];
    if (base + 3 < n) d3 = in[base + 3];
    int ts = d0 + d1 + d2 + d3;
    s[t] = ts;
    __syncthreads();
    for (int off = 1; off < 256; off <<= 1) {
        int v = (t >= off) ? s[t - off] : 0;
        __syncthreads();
        s[t] += v;
        __syncthreads();
    }
    int excl = s[t] - ts + bbase;
    if (base + 0 < n) out[base + 0] = excl;
    if (base + 1 < n) out[base + 1] = excl + d0;
    if (base + 2 < n) out[base + 2] = excl + d0 + d1;
    if (base + 3 < n) out[base + 3] = excl + d0 + d1 + d2;
}

// ---------------- partition: scatter to bins (pre-scanned, LDS cursors) ----------------

__global__ void k_pass2(const int* __restrict__ src, const int* __restrict__ dst,
                        const int* __restrict__ hist_scan, int* __restrict__ recs) {
    __shared__ int curs[NBINS];
    if (threadIdx.x < NBINS) curs[threadIdx.x] = hist_scan[threadIdx.x * PB + blockIdx.x];
    __syncthreads();
    int base = blockIdx.x * EPB;
    for (int i = threadIdx.x; i < EPB; i += 256) {
        int e = base + i;
        int s = src[e], d = dst[e];
        int pos = atomicAdd(&curs[d >> 9], 1);
        recs[pos] = s | ((d & 511) << 17);            // src:17b | dst_local:9b
    }
}

// ---------------- fused per-bin: degree hist + dinv + row_start scan + CSR scatter ----------------

__global__ void k_degsort(const int* __restrict__ recs, const int* __restrict__ hist_scan,
                          int* __restrict__ deg, float* __restrict__ dinv,
                          int* __restrict__ row_start, int* __restrict__ csr) {
    __shared__ int cnt[BINW];
    __shared__ int scn[BINW];
    int bin = blockIdx.x, t = threadIdx.x;
    cnt[t] = 0;
    __syncthreads();
    int s0 = hist_scan[bin * PB];
    int s1 = (bin + 1 < NBINS) ? hist_scan[(bin + 1) * PB] : NE;
    for (int r = s0 + t; r < s1; r += BINW)
        atomicAdd(&cnt[((unsigned)recs[r]) >> 17], 1);
    __syncthreads();
    // inclusive scan of cnt into scn
    scn[t] = cnt[t];
    __syncthreads();
    for (int off = 1; off < BINW; off <<= 1) {
        int v = (t >= off) ? scn[t - off] : 0;
        __syncthreads();
        scn[t] += v;
        __syncthreads();
    }
    int node = bin * BINW + t;
    int rs = s0 + scn[t] - cnt[t];   // exclusive
    if (node < NN) {
        int c = cnt[t];
        deg[node]       = c;
        dinv[node]      = (c > 0) ? rsqrtf((float)c) : 0.f;
        row_start[node] = rs;
    }
    scn[t] = rs;                      // cursor
    __syncthreads();
    for (int r = s0 + t; r < s1; r += BINW) {
        int rec = recs[r];
        int pos = atomicAdd(&scn[((unsigned)rec) >> 17], 1);
        csr[pos] = rec & 0x1FFFF;     // src only; norm weights factorized into dinv scaling
    }
}

// ---------------- layer 1 dense transform (A fp16, pre-scaled by dinv) ----------------

__global__ void k_transform1(const float* __restrict__ x, const float* __restrict__ iw,
                             const float* __restrict__ rw, const float* __restrict__ b1,
                             const float* __restrict__ dinv,
                             __half* __restrict__ A, float* __restrict__ R) {
    __shared__ float xs[16 * FEA];
    __shared__ float w0[KS * FEA * HID];
    __shared__ float wr[KS * FEA * HID];
    __shared__ float bb[KH];
    int n0 = blockIdx.x * 16;
    for (int i = threadIdx.x; i < KS * FEA * HID; i += 256) { w0[i] = iw[i]; wr[i] = rw[i]; }
    if (threadIdx.x < KH) bb[threadIdx.x] = b1[threadIdx.x];
    for (int i = threadIdx.x; i < 16 * FEA; i += 256) xs[i] = x[n0 * FEA + i];
    __syncthreads();
    for (int it = threadIdx.x; it < 16 * KH; it += 256) {
        int nl = it / KH, j = it % KH;
        int k = j >> 4, hh = j & 15;
        float a0 = 0.f, aR = bb[j];
        const float* wp0 = &w0[k * FEA * HID + hh];
        const float* wpr = &wr[k * FEA * HID + hh];
        const float* xp  = &xs[nl * FEA];
        #pragma unroll
        for (int f = 0; f < FEA; ++f) {
            float xv = xp[f];
            a0 += xv * wp0[f * HID];
            aR += xv * wpr[f * HID];
        }
        int n = n0 + nl;
        A[n * KH + j] = __float2half(a0 * dinv[n]);
        R[n * KH + j] = aR;
    }
}

// ---------------- SpMM 48-wide: fp16 gather, shfl-broadcast CSR, optional fused 16x16 gemm ----------------

template <bool FUSEW>
__global__ void k_spmm48(const __half* __restrict__ Asrc, const float* __restrict__ R,
                         const int* __restrict__ row_start, const int* __restrict__ deg,
                         const float* __restrict__ dinv, const int* __restrict__ csr,
                         const float* __restrict__ w1, __half* __restrict__ Bout) {
    __shared__ float w1s[FUSEW ? KS * HID * HID : 1];
    if (FUSEW) {
        for (int i = threadIdx.x; i < KS * HID * HID; i += 256) w1s[i] = w1[i];
        __syncthreads();
    }
    int node = (blockIdx.x * 256 + threadIdx.x) >> 6;   // one wave per node
    int lane = threadIdx.x & 63;
    int col  = (lane < KH) ? lane : 0;                  // keep all 64 lanes alive for shfl
    int start = __builtin_amdgcn_readfirstlane(row_start[node]);
    int d     = __builtin_amdgcn_readfirstlane(deg[node]);
    float r   = R[node * KH + col];
    float dv  = dinv[node];
    float acc = 0.f;
    for (int base = 0; base < d; base += 64) {
        int nb  = min(64, d - base);
        int myc = csr[start + base + min(lane, nb - 1)];  // 1 coalesced load / 64 edges
        int e = 0;
        for (; e + 4 <= nb; e += 4) {
            int c0 = __shfl(myc, e + 0, 64);
            int c1 = __shfl(myc, e + 1, 64);
            int c2 = __shfl(myc, e + 2, 64);
            int c3 = __shfl(myc, e + 3, 64);
            float a0 = __half2float(Asrc[c0 * KH + col]);
            float a1 = __half2float(Asrc[c1 * KH + col]);
            float a2 = __half2float(Asrc[c2 * KH + col]);
            float a3 = __half2float(Asrc[c3 * KH + col]);
            acc += a0; acc += a1; acc += a2; acc += a3;
        }
        for (; e < nb; ++e) {
            int c = __shfl(myc, e, 64);
            acc += __half2float(Asrc[c * KH + col]);
        }
    }
    acc = fmaxf(acc * dv + r, 0.f);   // post-scale dinv[dst]; both layer-1 steps relu
    if (FUSEW) {
        // A'[n, k*16+p] = (sum_h relu_out[n, k*16+h] * w1[k][h][p]) * dinv[n]
        int k = col >> 4, p = col & 15, k16 = k << 4;
        float a2s = 0.f;
        #pragma unroll
        for (int h = 0; h < HID; ++h)
            a2s += __shfl(acc, k16 + h, 64) * w1s[k * 256 + h * 16 + p];
        if (lane < KH) Bout[node * KH + lane] = __float2half(a2s * dv);
    } else {
        if (lane < KH) Bout[node * KH + lane] = __float2half(acc);
    }
}

// ---------------- fused mean+relu+transform2 (reads fp16 L1 out; A2 pre-scaled) ----------------

__global__ void k_mt2(const __half* __restrict__ L1, const float* __restrict__ iw,
                      const float* __restrict__ rw, const float* __restrict__ b2,
                      const float* __restrict__ dinv,
                      float* __restrict__ A2, float* __restrict__ R2) {
    __shared__ float wi[KS * HID * OUTC];
    __shared__ float wr_[KS * HID * OUTC];
    __shared__ float bb[KO];
    if (threadIdx.x < KS * HID * OUTC) { wi[threadIdx.x] = iw[threadIdx.x]; wr_[threadIdx.x] = rw[threadIdx.x]; }
    if (threadIdx.x < KO) bb[threadIdx.x] = b2[threadIdx.x];
    __syncthreads();
    int n = blockIdx.x * 256 + threadIdx.x;
    if (n >= NN) return;
    const __half2* hp = (const __half2*)(L1 + (size_t)n * KH);
    float v[KH];
    #pragma unroll
    for (int q = 0; q < 24; ++q) {
        float2 f = __half22float2(hp[q]);
        v[q * 2 + 0] = f.x; v[q * 2 + 1] = f.y;
    }
    float h[HID];
    #pragma unroll
    for (int hh = 0; hh < HID; ++hh)
        h[hh] = fmaxf((v[hh] + v[16 + hh] + v[32 + hh]) * (1.f / 3.f), 0.f);
    float dv = dinv[n];
    #pragma unroll
    for (int k = 0; k < KS; ++k) {
        #pragma unroll
        for (int o = 0; o < OUTC; ++o) {
            float a = 0.f, r = bb[k * 2 + o];
            #pragma unroll
            for (int hh = 0; hh < HID; ++hh) {
                a += h[hh] * wi[k * 32 + hh * 2 + o];
                r += h[hh] * wr_[k * 32 + hh * 2 + o];
            }
            A2[n * KO + k * 2 + o] = a * dv;
            R2[n * KO + k * 2 + o] = r;
        }
    }
}

// ---------------- SpMM 6-wide #1: fused 2x2 gemm (w2), output pre-scaled ----------------

__global__ void k_spmm6_g(const float* __restrict__ Asrc, const float* __restrict__ R2,
                          const int* __restrict__ row_start, const int* __restrict__ deg,
                          const float* __restrict__ dinv, const int* __restrict__ csr,
                          const float* __restrict__ w2, float* __restrict__ Bout) {
    __shared__ float ws[KS * OUTC * OUTC];
    if (threadIdx.x < KS * OUTC * OUTC) ws[threadIdx.x] = w2[threadIdx.x];
    __syncthreads();
    int t = blockIdx.x * 256 + threadIdx.x;
    int node = t / KO, j = t % KO;
    bool active = node < NN;
    float acc = 0.f, r = 0.f, dv = 0.f;
    int start = 0, d = 0;
    if (active) {
        start = row_start[node];
        d     = deg[node];
        r     = R2[node * KO + j];
        dv    = dinv[node];
    }
    int e = 0;
    for (; e + 4 <= d; e += 4) {
        int c0 = csr[start + e + 0];
        int c1 = csr[start + e + 1];
        int c2 = csr[start + e + 2];
        int c3 = csr[start + e + 3];
        acc += Asrc[c0 * KO + j];
        acc += Asrc[c1 * KO + j];
        acc += Asrc[c2 * KO + j];
        acc += Asrc[c3 * KO + j];
    }
    for (; e < d; ++e)
        acc += Asrc[csr[start + e] * KO + j];
    float v = acc * dv + r;
    float other = __shfl_xor(v, 1, 64);
    if (active) {
        int k = j >> 1, p = j & 1;
        float v0 = (p == 0) ? v : other;
        float v1 = (p == 0) ? other : v;
        Bout[node * KO + j] = (v0 * ws[k * 4 + p] + v1 * ws[k * 4 + 2 + p]) * dv;
    }
}

// ---------------- SpMM 6-wide #2: fused mean + log_softmax (10 nodes/wave) ----------------

__global__ void k_spmm6_f(const float* __restrict__ Asrc, const float* __restrict__ R2,
                          const int* __restrict__ row_start, const int* __restrict__ deg,
                          const float* __restrict__ dinv, const int* __restrict__ csr,
                          float* __restrict__ out) {
    int wave = threadIdx.x >> 6;
    int l    = threadIdx.x & 63;
    int nl   = l / 6;            // 0..10 (10 = inactive)
    int j    = l - nl * 6;
    bool active = nl < 10;
    int node = blockIdx.x * 40 + wave * 10 + nl;
    float acc = 0.f, r = 0.f, dv = 0.f;
    int start = 0, d = 0;
    if (active) {
        start = row_start[node];
        d     = deg[node];
        r     = R2[node * KO + j];
        dv    = dinv[node];
    }
    int e = 0;
    for (; e + 4 <= d; e += 4) {
        int c0 = csr[start + e + 0];
        int c1 = csr[start + e + 1];
        int c2 = csr[start + e + 2];
        int c3 = csr[start + e + 3];
        acc += Asrc[c0 * KO + j];
        acc += Asrc[c1 * KO + j];
        acc += Asrc[c2 * KO + j];
        acc += Asrc[c3 * KO + j];
    }
    for (; e < d; ++e)
        acc += Asrc[csr[start + e] * KO + j];
    float v = acc * dv + r;
    int base = nl * 6;
    float o0 = (__shfl(v, base + 0, 64) + __shfl(v, base + 2, 64) + __shfl(v, base + 4, 64)) * (1.f / 3.f);
    float o1 = (__shfl(v, base + 1, 64) + __shfl(v, base + 3, 64) + __shfl(v, base + 5, 64)) * (1.f / 3.f);
    if (active && j == 0) {
        float m = fmaxf(o0, o1);
        float ls = m + logf(expf(o0 - m) + expf(o1 - m));
        *(float2*)(out + (size_t)node * 2) = make_float2(o0 - ls, o1 - ls);
    }
}

// ---------------- host ----------------

extern "C" void kernel_launch(void* const* d_in, const int* in_sizes, int n_in,
                              void* d_out, int out_size, void* d_ws, size_t ws_size,
                              hipStream_t stream) {
    const float* x   = (const float*)d_in[0];
    const int*   ei  = (const int*)d_in[1];
    const float* iw1 = (const float*)d_in[2];
    const float* w1  = (const float*)d_in[3];
    const float* rw1 = (const float*)d_in[4];
    const float* b1  = (const float*)d_in[5];
    const float* iw2 = (const float*)d_in[6];
    const float* w2  = (const float*)d_in[7];
    const float* rw2 = (const float*)d_in[8];
    const float* b2  = (const float*)d_in[9];
    const int* src = ei;
    const int* dst = ei + NE;
    float* out = (float*)d_out;

    char* ws = (char*)d_ws;
    size_t o = 0;
    int*    deg       = (int*)(ws + o);    o += (size_t)NN * 4;
    int*    row_start = (int*)(ws + o);    o += (size_t)NN * 4;
    float*  dinv      = (float*)(ws + o);  o += (size_t)NN * 4;
    int*    hist      = (int*)(ws + o);    o += (size_t)M1 * 4;
    int*    hist_scan = (int*)(ws + o);    o += (size_t)M1 * 4;
    int*    partials  = (int*)(ws + o);    o += 128 * 4;
    int*    csr       = (int*)(ws + o);    o += (size_t)NE * 4;        // 12.8MB (src only)
    __half* A         = (__half*)(ws + o); o += (size_t)NN * KH * 2;   // 9.6MB fp16
    float*  R         = (float*)(ws + o);  o += (size_t)NN * KH * 4;   // 19.2MB
    __half* B         = (__half*)(ws + o); o += (size_t)NN * KH * 2;   // 9.6MB fp16
    // overlays
    int*    recs  = (int*)A;                 // 12.8MB spans A + head of R; dead before transform1
    __half* L1f   = A;                       // spmm48#2 output (doesn't read A)
    float*  A2    = R;                       // layer-2 buffers live in R (dead after spmm48#2)
    float*  R2    = R + (size_t)NN * KO;
    float*  C2    = R + (size_t)NN * KO * 2;

    // ---- CSR build (5 dispatches) ----
    k_hist       <<<PB, 256, 0, stream>>>(dst, hist);
    k_partial    <<<NSCB, 256, 0, stream>>>(hist, partials, M1);
    k_downsweepF <<<NSCB, 256, 0, stream>>>(hist, partials, hist_scan, M1);
    k_pass2      <<<PB, 256, 0, stream>>>(src, dst, hist_scan, recs);
    k_degsort    <<<NBINS, BINW, 0, stream>>>(recs, hist_scan, deg, dinv, row_start, csr);

    // ---- layer 1 ----
    k_transform1    <<<NN / 16, 256, 0, stream>>>(x, iw1, rw1, b1, dinv, A, R);
    k_spmm48<true>  <<<NN / 4, 256, 0, stream>>>(A, R, row_start, deg, dinv, csr, w1, B);
    k_spmm48<false> <<<NN / 4, 256, 0, stream>>>(B, R, row_start, deg, dinv, csr, w1, L1f);

    // ---- layer 2 ----
    k_mt2      <<<(NN + 255) / 256, 256, 0, stream>>>(L1f, iw2, rw2, b2, dinv, A2, R2);
    k_spmm6_g  <<<(NN * KO + 255) / 256, 256, 0, stream>>>(A2, R2, row_start, deg, dinv, csr, w2, C2);
    k_spmm6_f  <<<NN / 40, 256, 0, stream>>>(C2, R2, row_start, deg, dinv, csr, out);
}

// Round 5
// 344.099 us; speedup vs baseline: 2.7890x; 1.0930x over previous
//
#include <hip/hip_runtime.h>
#include <hip/hip_fp16.h>
#include <math.h>

#define NN 100000
#define NE 3200000
#define FEA 67
#define HID 16
#define OUTC 2
#define KS 3
#define KH 48   /* KS*HID */
#define KO 6    /* KS*OUTC */
#define PAD 64  /* padded fp16 row stride: 128B = 1 cache line */

#define PB 512          /* partition blocks */
#define EPB 6250        /* edges per partition block (PB*EPB == NE) */
#define BINW 512        /* nodes per bin */
#define NBINS 196       /* ceil(NN/BINW) */
#define M1 (NBINS * PB) /* 100352 */
#define NSCB 98         /* scan blocks: 98*1024 == M1 exactly */

// ---------------- partition: histogram ----------------

__global__ void k_hist(const int* __restrict__ dst, int* __restrict__ hist) {
    __shared__ int h[NBINS];
    if (threadIdx.x < NBINS) h[threadIdx.x] = 0;
    __syncthreads();
    int base = blockIdx.x * EPB;
    for (int i = threadIdx.x; i < EPB; i += 256)
        atomicAdd(&h[dst[base + i] >> 9], 1);
    __syncthreads();
    if (threadIdx.x < NBINS) hist[threadIdx.x * PB + blockIdx.x] = h[threadIdx.x];
}

// ---------------- 2-kernel exclusive scan ----------------

__global__ void k_partial(const int* __restrict__ in, int* __restrict__ partials, int n) {
    __shared__ int s[256];
    int base = blockIdx.x * 1024;
    int acc = 0;
    for (int i = threadIdx.x; i < 1024; i += 256) {
        int idx = base + i;
        if (idx < n) acc += in[idx];
    }
    s[threadIdx.x] = acc;
    __syncthreads();
    for (int off = 128; off > 0; off >>= 1) {
        if (threadIdx.x < off) s[threadIdx.x] += s[threadIdx.x + off];
        __syncthreads();
    }
    if (threadIdx.x == 0) partials[blockIdx.x] = s[0];
}

__global__ void k_downsweepF(const int* __restrict__ in, const int* __restrict__ partials,
                             int* __restrict__ out, int n) {
    __shared__ int ps[256];
    __shared__ int s[256];
    int t = threadIdx.x;
    ps[t] = (t < NSCB) ? partials[t] : 0;
    __syncthreads();
    for (int off = 1; off < 256; off <<= 1) {
        int v = (t >= off) ? ps[t - off] : 0;
        __syncthreads();
        ps[t] += v;
        __syncthreads();
    }
    int bbase = (blockIdx.x > 0) ? ps[blockIdx.x - 1] : 0;

    int base = blockIdx.x * 1024 + t * 4;
    int d0 = 0, d1 = 0, d2 = 0, d3 = 0;
    if (base + 0 < n) d0 = in[base + 0];
    if (base + 1 < n) d1 = in[base + 1];
    if (base + 2 < n) d2 = in[base + 2];
    if (base + 3 < n) d3 = in[base + 3];
    int ts = d0 + d1 + d2 + d3;
    s[t] = ts;
    __syncthreads();
    for (int off = 1; off < 256; off <<= 1) {
        int v = (t >= off) ? s[t - off] : 0;
        __syncthreads();
        s[t] += v;
        __syncthreads();
    }
    int excl = s[t] - ts + bbase;
    if (base + 0 < n) out[base + 0] = excl;
    if (base + 1 < n) out[base + 1] = excl + d0;
    if (base + 2 < n) out[base + 2] = excl + d0 + d1;
    if (base + 3 < n) out[base + 3] = excl + d0 + d1 + d2;
}

// ---------------- partition: scatter to bins ----------------

__global__ void k_pass2(const int* __restrict__ src, const int* __restrict__ dst,
                        const int* __restrict__ hist_scan, int* __restrict__ recs) {
    __shared__ int curs[NBINS];
    if (threadIdx.x < NBINS) curs[threadIdx.x] = hist_scan[threadIdx.x * PB + blockIdx.x];
    __syncthreads();
    int base = blockIdx.x * EPB;
    for (int i = threadIdx.x; i < EPB; i += 256) {
        int e = base + i;
        int s = src[e], d = dst[e];
        int pos = atomicAdd(&curs[d >> 9], 1);
        recs[pos] = s | ((d & 511) << 17);            // src:17b | dst_local:9b
    }
}

// ---------------- fused per-bin: degree + dinv + row_start + CSR scatter ----------------

__global__ void k_degsort(const int* __restrict__ recs, const int* __restrict__ hist_scan,
                          int* __restrict__ deg, float* __restrict__ dinv,
                          int* __restrict__ row_start, int* __restrict__ csr) {
    __shared__ int cnt[BINW];
    __shared__ int scn[BINW];
    int bin = blockIdx.x, t = threadIdx.x;
    cnt[t] = 0;
    __syncthreads();
    int s0 = hist_scan[bin * PB];
    int s1 = (bin + 1 < NBINS) ? hist_scan[(bin + 1) * PB] : NE;
    for (int r = s0 + t; r < s1; r += BINW)
        atomicAdd(&cnt[((unsigned)recs[r]) >> 17], 1);
    __syncthreads();
    scn[t] = cnt[t];
    __syncthreads();
    for (int off = 1; off < BINW; off <<= 1) {
        int v = (t >= off) ? scn[t - off] : 0;
        __syncthreads();
        scn[t] += v;
        __syncthreads();
    }
    int node = bin * BINW + t;
    int rs = s0 + scn[t] - cnt[t];
    if (node < NN) {
        int c = cnt[t];
        deg[node]       = c;
        dinv[node]      = (c > 0) ? rsqrtf((float)c) : 0.f;
        row_start[node] = rs;
    }
    scn[t] = rs;
    __syncthreads();
    for (int r = s0 + t; r < s1; r += BINW) {
        int rec = recs[r];
        int pos = atomicAdd(&scn[((unsigned)rec) >> 17], 1);
        csr[pos] = rec & 0x1FFFF;
    }
}

// ---------------- layer 1 dense transform (A fp16 padded-64, pre-scaled; pair stores) ----------------

__global__ void k_transform1(const float* __restrict__ x, const float* __restrict__ iw,
                             const float* __restrict__ rw, const float* __restrict__ b1,
                             const float* __restrict__ dinv,
                             __half* __restrict__ A, __half* __restrict__ Bpad,
                             float* __restrict__ R) {
    if (blockIdx.x == NN / 16) {   // zero the pad rows (index NN) of A and B
        int t = threadIdx.x;
        if (t < PAD) A[(size_t)NN * PAD + t] = __float2half(0.f);
        else if (t < 2 * PAD) Bpad[(size_t)NN * PAD + (t - PAD)] = __float2half(0.f);
        return;
    }
    __shared__ float xs[16 * FEA];
    __shared__ float w0[KS * FEA * HID];
    __shared__ float wr[KS * FEA * HID];
    __shared__ float bb[KH];
    int n0 = blockIdx.x * 16;
    for (int i = threadIdx.x; i < KS * FEA * HID; i += 256) { w0[i] = iw[i]; wr[i] = rw[i]; }
    if (threadIdx.x < KH) bb[threadIdx.x] = b1[threadIdx.x];
    for (int i = threadIdx.x; i < 16 * FEA; i += 256) xs[i] = x[n0 * FEA + i];
    __syncthreads();
    for (int it = threadIdx.x; it < 16 * 24; it += 256) {
        int nl = it / 24, m = it % 24;
        int j0 = 2 * m;
        int k = j0 >> 4, h0 = j0 & 15;
        const float* wp0 = &w0[k * FEA * HID + h0];
        const float* wpr = &wr[k * FEA * HID + h0];
        const float* xp  = &xs[nl * FEA];
        float a0 = 0.f, a1 = 0.f, r0 = bb[j0], r1 = bb[j0 + 1];
        #pragma unroll
        for (int f = 0; f < FEA; ++f) {
            float xv = xp[f];
            a0 += xv * wp0[f * HID];
            a1 += xv * wp0[f * HID + 1];
            r0 += xv * wpr[f * HID];
            r1 += xv * wpr[f * HID + 1];
        }
        int n = n0 + nl;
        float dvn = dinv[n];
        ((__half2*)A)[(size_t)n * (PAD / 2) + m] =
            __halves2half2(__float2half_rn(a0 * dvn), __float2half_rn(a1 * dvn));
        *(float2*)&R[(size_t)n * KH + j0] = make_float2(r0, r1);
    }
}

// ---------------- SpMM 48-wide: pair scheme (2 edges/wave-iter, half2 gathers) ----------------

template <bool FUSEW>
__global__ void k_spmm48(const __half2* __restrict__ Asrc,   // row stride PAD/2 half2
                         const float* __restrict__ R,
                         const int* __restrict__ row_start, const int* __restrict__ deg,
                         const float* __restrict__ dinv, const int* __restrict__ csr,
                         const float* __restrict__ w1, __half2* __restrict__ Bout) {
    __shared__ float w1s[FUSEW ? KS * HID * HID : 1];
    if (FUSEW) {
        for (int i = threadIdx.x; i < KS * HID * HID; i += 256) w1s[i] = w1[i];
        __syncthreads();
    }
    int node = (blockIdx.x * 256 + threadIdx.x) >> 6;   // one wave per node
    int lane = threadIdx.x & 63;
    int eo   = lane >> 5;           // edge parity within pair
    int cl   = lane & 31;           // col-pair index (cols 2cl, 2cl+1)
    int start = __builtin_amdgcn_readfirstlane(row_start[node]);
    int d     = __builtin_amdgcn_readfirstlane(deg[node]);
    float dv  = dinv[node];
    float ax = 0.f, ay = 0.f;
    for (int b = 0; b < d; b += 64) {
        int nb  = min(64, d - b);
        int myc = csr[start + b + lane];    // one coalesced load per 64-edge chunk
        int npf = nb >> 1;                  // full pairs
        int p = 0;
        for (; p + 4 <= npf; p += 4) {
            int c0 = __shfl(myc, 2 * (p + 0) + eo, 64);
            int c1 = __shfl(myc, 2 * (p + 1) + eo, 64);
            int c2 = __shfl(myc, 2 * (p + 2) + eo, 64);
            int c3 = __shfl(myc, 2 * (p + 3) + eo, 64);
            float2 f0 = __half22float2(Asrc[(size_t)c0 * (PAD / 2) + cl]);
            float2 f1 = __half22float2(Asrc[(size_t)c1 * (PAD / 2) + cl]);
            float2 f2 = __half22float2(Asrc[(size_t)c2 * (PAD / 2) + cl]);
            float2 f3 = __half22float2(Asrc[(size_t)c3 * (PAD / 2) + cl]);
            ax += f0.x + f1.x; ay += f0.y + f1.y;
            ax += f2.x + f3.x; ay += f2.y + f3.y;
        }
        for (; p < npf; ++p) {
            int c = __shfl(myc, 2 * p + eo, 64);
            float2 f = __half22float2(Asrc[(size_t)c * (PAD / 2) + cl]);
            ax += f.x; ay += f.y;
        }
        if (nb & 1) {                        // odd tail: only parity-0 edge exists
            int c = __shfl(myc, nb - 1, 64);
            c = (eo == 0) ? c : NN;          // parity-1 lanes add the zeroed pad row
            float2 f = __half22float2(Asrc[(size_t)c * (PAD / 2) + cl]);
            ax += f.x; ay += f.y;
        }
    }
    // combine edge parities
    ax += __shfl_xor(ax, 32, 64);
    ay += __shfl_xor(ay, 32, 64);
    // root + relu (both layer-1 propagates end in relu)
    float2 r2 = make_float2(0.f, 0.f);
    if (cl < 24) r2 = *(const float2*)&R[(size_t)node * KH + 2 * cl];
    float vx = fmaxf(ax * dv + r2.x, 0.f);
    float vy = fmaxf(ay * dv + r2.y, 0.f);
    if (FUSEW) {
        // out[k*16+p0], out[k*16+p0+1] = sum_h in[k*16+h] * w1[k][h][p]
        int k  = cl >> 3;              // (2cl)>>4
        int p0 = (2 * cl) & 15;
        float o0 = 0.f, o1 = 0.f;
        #pragma unroll
        for (int h2 = 0; h2 < 8; ++h2) {
            float ix = __shfl(vx, k * 8 + h2, 64);   // in[k*16 + 2h2]
            float iy = __shfl(vy, k * 8 + h2, 64);   // in[k*16 + 2h2+1]
            o0 += ix * w1s[k * 256 + (2 * h2) * 16 + p0]     + iy * w1s[k * 256 + (2 * h2 + 1) * 16 + p0];
            o1 += ix * w1s[k * 256 + (2 * h2) * 16 + p0 + 1] + iy * w1s[k * 256 + (2 * h2 + 1) * 16 + p0 + 1];
        }
        if (eo == 0 && cl < 24)
            Bout[(size_t)node * (PAD / 2) + cl] =
                __halves2half2(__float2half_rn(o0 * dv), __float2half_rn(o1 * dv));
    } else {
        if (eo == 0 && cl < 24)
            Bout[(size_t)node * (PAD / 2) + cl] =
                __halves2half2(__float2half_rn(vx), __float2half_rn(vy));
    }
}

// ---------------- fused mean+relu+transform2 (reads fp16 padded L1; A2 pre-scaled) ----------------

__global__ void k_mt2(const __half* __restrict__ L1, const float* __restrict__ iw,
                      const float* __restrict__ rw, const float* __restrict__ b2,
                      const float* __restrict__ dinv,
                      float* __restrict__ A2, float* __restrict__ R2) {
    __shared__ float wi[KS * HID * OUTC];
    __shared__ float wr_[KS * HID * OUTC];
    __shared__ float bb[KO];
    if (threadIdx.x < KS * HID * OUTC) { wi[threadIdx.x] = iw[threadIdx.x]; wr_[threadIdx.x] = rw[threadIdx.x]; }
    if (threadIdx.x < KO) bb[threadIdx.x] = b2[threadIdx.x];
    __syncthreads();
    int n = blockIdx.x * 256 + threadIdx.x;
    if (n >= NN) return;
    const __half2* hp = (const __half2*)(L1 + (size_t)n * PAD);
    float v[KH];
    #pragma unroll
    for (int q = 0; q < 24; ++q) {
        float2 f = __half22float2(hp[q]);
        v[q * 2 + 0] = f.x; v[q * 2 + 1] = f.y;
    }
    float h[HID];
    #pragma unroll
    for (int hh = 0; hh < HID; ++hh)
        h[hh] = fmaxf((v[hh] + v[16 + hh] + v[32 + hh]) * (1.f / 3.f), 0.f);
    float dv = dinv[n];
    #pragma unroll
    for (int k = 0; k < KS; ++k) {
        #pragma unroll
        for (int o = 0; o < OUTC; ++o) {
            float a = 0.f, r = bb[k * 2 + o];
            #pragma unroll
            for (int hh = 0; hh < HID; ++hh) {
                a += h[hh] * wi[k * 32 + hh * 2 + o];
                r += h[hh] * wr_[k * 32 + hh * 2 + o];
            }
            A2[n * KO + k * 2 + o] = a * dv;
            R2[n * KO + k * 2 + o] = r;
        }
    }
}

// ---------------- SpMM 6-wide #1: fused 2x2 gemm (w2), output pre-scaled ----------------

__global__ void k_spmm6_g(const float* __restrict__ Asrc, const float* __restrict__ R2,
                          const int* __restrict__ row_start, const int* __restrict__ deg,
                          const float* __restrict__ dinv, const int* __restrict__ csr,
                          const float* __restrict__ w2, float* __restrict__ Bout) {
    __shared__ float ws[KS * OUTC * OUTC];
    if (threadIdx.x < KS * OUTC * OUTC) ws[threadIdx.x] = w2[threadIdx.x];
    __syncthreads();
    int t = blockIdx.x * 256 + threadIdx.x;
    int node = t / KO, j = t % KO;
    bool active = node < NN;
    float acc = 0.f, r = 0.f, dv = 0.f;
    int start = 0, d = 0;
    if (active) {
        start = row_start[node];
        d     = deg[node];
        r     = R2[node * KO + j];
        dv    = dinv[node];
    }
    int e = 0;
    for (; e + 4 <= d; e += 4) {
        int c0 = csr[start + e + 0];
        int c1 = csr[start + e + 1];
        int c2 = csr[start + e + 2];
        int c3 = csr[start + e + 3];
        acc += Asrc[c0 * KO + j];
        acc += Asrc[c1 * KO + j];
        acc += Asrc[c2 * KO + j];
        acc += Asrc[c3 * KO + j];
    }
    for (; e < d; ++e)
        acc += Asrc[csr[start + e] * KO + j];
    float v = acc * dv + r;
    float other = __shfl_xor(v, 1, 64);
    if (active) {
        int k = j >> 1, p = j & 1;
        float v0 = (p == 0) ? v : other;
        float v1 = (p == 0) ? other : v;
        Bout[node * KO + j] = (v0 * ws[k * 4 + p] + v1 * ws[k * 4 + 2 + p]) * dv;
    }
}

// ---------------- SpMM 6-wide #2: fused mean + log_softmax (10 nodes/wave) ----------------

__global__ void k_spmm6_f(const float* __restrict__ Asrc, const float* __restrict__ R2,
                          const int* __restrict__ row_start, const int* __restrict__ deg,
                          const float* __restrict__ dinv, const int* __restrict__ csr,
                          float* __restrict__ out) {
    int wave = threadIdx.x >> 6;
    int l    = threadIdx.x & 63;
    int nl   = l / 6;            // 0..10 (10 = inactive)
    int j    = l - nl * 6;
    bool active = nl < 10;
    int node = blockIdx.x * 40 + wave * 10 + nl;
    float acc = 0.f, r = 0.f, dv = 0.f;
    int start = 0, d = 0;
    if (active) {
        start = row_start[node];
        d     = deg[node];
        r     = R2[node * KO + j];
        dv    = dinv[node];
    }
    int e = 0;
    for (; e + 4 <= d; e += 4) {
        int c0 = csr[start + e + 0];
        int c1 = csr[start + e + 1];
        int c2 = csr[start + e + 2];
        int c3 = csr[start + e + 3];
        acc += Asrc[c0 * KO + j];
        acc += Asrc[c1 * KO + j];
        acc += Asrc[c2 * KO + j];
        acc += Asrc[c3 * KO + j];
    }
    for (; e < d; ++e)
        acc += Asrc[csr[start + e] * KO + j];
    float v = acc * dv + r;
    int base = nl * 6;
    float o0 = (__shfl(v, base + 0, 64) + __shfl(v, base + 2, 64) + __shfl(v, base + 4, 64)) * (1.f / 3.f);
    float o1 = (__shfl(v, base + 1, 64) + __shfl(v, base + 3, 64) + __shfl(v, base + 5, 64)) * (1.f / 3.f);
    if (active && j == 0) {
        float m = fmaxf(o0, o1);
        float ls = m + logf(expf(o0 - m) + expf(o1 - m));
        *(float2*)(out + (size_t)node * 2) = make_float2(o0 - ls, o1 - ls);
    }
}

// ---------------- host ----------------

extern "C" void kernel_launch(void* const* d_in, const int* in_sizes, int n_in,
                              void* d_out, int out_size, void* d_ws, size_t ws_size,
                              hipStream_t stream) {
    const float* x   = (const float*)d_in[0];
    const int*   ei  = (const int*)d_in[1];
    const float* iw1 = (const float*)d_in[2];
    const float* w1  = (const float*)d_in[3];
    const float* rw1 = (const float*)d_in[4];
    const float* b1  = (const float*)d_in[5];
    const float* iw2 = (const float*)d_in[6];
    const float* w2  = (const float*)d_in[7];
    const float* rw2 = (const float*)d_in[8];
    const float* b2  = (const float*)d_in[9];
    const int* src = ei;
    const int* dst = ei + NE;
    float* out = (float*)d_out;

    char* ws = (char*)d_ws;
    size_t o = 0;
    int*    deg       = (int*)(ws + o);    o += (size_t)NN * 4;
    int*    row_start = (int*)(ws + o);    o += (size_t)NN * 4;
    float*  dinv      = (float*)(ws + o);  o += (size_t)NN * 4;
    int*    hist      = (int*)(ws + o);    o += (size_t)M1 * 4;
    int*    hist_scan = (int*)(ws + o);    o += (size_t)M1 * 4;
    int*    partials  = (int*)(ws + o);    o += 128 * 4;
    int*    csr       = (int*)(ws + o);    o += (size_t)(NE + 64) * 4;       // +64 chunk-read slack
    __half* A         = (__half*)(ws + o); o += (size_t)(NN + 1) * PAD * 2;  // 12.8MB (padded rows + zero row)
    float*  R         = (float*)(ws + o);  o += (size_t)NN * KH * 4;         // 19.2MB
    __half* B         = (__half*)(ws + o); o += (size_t)(NN + 1) * PAD * 2;  // 12.8MB
    // overlays
    int*    recs  = (int*)A;                 // NE*4 = 12.8MB fits in A region; dead before transform1
    __half* L1f   = A;                       // spmm48#2 output (reads B, not A)
    float*  A2    = R;                       // layer-2 buffers live in R (dead after spmm48#2)
    float*  R2    = R + (size_t)NN * KO;
    float*  C2    = R + (size_t)NN * KO * 2;

    // ---- CSR build (5 dispatches) ----
    k_hist       <<<PB, 256, 0, stream>>>(dst, hist);
    k_partial    <<<NSCB, 256, 0, stream>>>(hist, partials, M1);
    k_downsweepF <<<NSCB, 256, 0, stream>>>(hist, partials, hist_scan, M1);
    k_pass2      <<<PB, 256, 0, stream>>>(src, dst, hist_scan, recs);
    k_degsort    <<<NBINS, BINW, 0, stream>>>(recs, hist_scan, deg, dinv, row_start, csr);

    // ---- layer 1 ----
    k_transform1    <<<NN / 16 + 1, 256, 0, stream>>>(x, iw1, rw1, b1, dinv, A, B, R);
    k_spmm48<true>  <<<NN / 4, 256, 0, stream>>>((const __half2*)A, R, row_start, deg, dinv, csr, w1, (__half2*)B);
    k_spmm48<false> <<<NN / 4, 256, 0, stream>>>((const __half2*)B, R, row_start, deg, dinv, csr, w1, (__half2*)L1f);

    // ---- layer 2 ----
    k_mt2      <<<(NN + 255) / 256, 256, 0, stream>>>(L1f, iw2, rw2, b2, dinv, A2, R2);
    k_spmm6_g  <<<(NN * KO + 255) / 256, 256, 0, stream>>>(A2, R2, row_start, deg, dinv, csr, w2, C2);
    k_spmm6_f  <<<NN / 40, 256, 0, stream>>>(C2, R2, row_start, deg, dinv, csr, out);
}

// Round 6
// 330.762 us; speedup vs baseline: 2.9015x; 1.0403x over previous
//
#include <hip/hip_runtime.h>
#include <hip/hip_fp16.h>
#include <math.h>

#define NN 100000
#define NE 3200000
#define FEA 67
#define HID 16
#define OUTC 2
#define KS 3
#define KH 48   /* KS*HID */
#define KO 6    /* KS*OUTC */
#define PAD 64  /* padded fp16 row stride: 128B = 1 cache line */

#define PB 512          /* partition blocks */
#define EPB 6250        /* edges per partition block (PB*EPB == NE) */
#define BINW 512        /* nodes per bin */
#define NBINS 196       /* ceil(NN/BINW) */
#define M1 (NBINS * PB) /* 100352 */
#define NSCB 98         /* scan blocks: 98*1024 == M1 exactly */

#define TBM 128               /* transform1 nodes per block */
#define TNB ((NN + TBM - 1) / TBM)   /* 782 */
#define XS_STRIDE 132         /* xT row stride (16B-aligned float4, conflict-spread) */
#define WT_STRIDE 68          /* wT row stride */

// ---------------- partition: histogram ----------------

__global__ void k_hist(const int* __restrict__ dst, int* __restrict__ hist) {
    __shared__ int h[NBINS];
    if (threadIdx.x < NBINS) h[threadIdx.x] = 0;
    __syncthreads();
    int base = blockIdx.x * EPB;
    for (int i = threadIdx.x; i < EPB; i += 256)
        atomicAdd(&h[dst[base + i] >> 9], 1);
    __syncthreads();
    if (threadIdx.x < NBINS) hist[threadIdx.x * PB + blockIdx.x] = h[threadIdx.x];
}

// ---------------- 2-kernel exclusive scan ----------------

__global__ void k_partial(const int* __restrict__ in, int* __restrict__ partials, int n) {
    __shared__ int s[256];
    int base = blockIdx.x * 1024;
    int acc = 0;
    for (int i = threadIdx.x; i < 1024; i += 256) {
        int idx = base + i;
        if (idx < n) acc += in[idx];
    }
    s[threadIdx.x] = acc;
    __syncthreads();
    for (int off = 128; off > 0; off >>= 1) {
        if (threadIdx.x < off) s[threadIdx.x] += s[threadIdx.x + off];
        __syncthreads();
    }
    if (threadIdx.x == 0) partials[blockIdx.x] = s[0];
}

__global__ void k_downsweepF(const int* __restrict__ in, const int* __restrict__ partials,
                             int* __restrict__ out, int n) {
    __shared__ int ps[256];
    __shared__ int s[256];
    int t = threadIdx.x;
    ps[t] = (t < NSCB) ? partials[t] : 0;
    __syncthreads();
    for (int off = 1; off < 256; off <<= 1) {
        int v = (t >= off) ? ps[t - off] : 0;
        __syncthreads();
        ps[t] += v;
        __syncthreads();
    }
    int bbase = (blockIdx.x > 0) ? ps[blockIdx.x - 1] : 0;

    int base = blockIdx.x * 1024 + t * 4;
    int d0 = 0, d1 = 0, d2 = 0, d3 = 0;
    if (base + 0 < n) d0 = in[base + 0];
    if (base + 1 < n) d1 = in[base + 1];
    if (base + 2 < n) d2 = in[base + 2];
    if (base + 3 < n) d3 = in[base + 3];
    int ts = d0 + d1 + d2 + d3;
    s[t] = ts;
    __syncthreads();
    for (int off = 1; off < 256; off <<= 1) {
        int v = (t >= off) ? s[t - off] : 0;
        __syncthreads();
        s[t] += v;
        __syncthreads();
    }
    int excl = s[t] - ts + bbase;
    if (base + 0 < n) out[base + 0] = excl;
    if (base + 1 < n) out[base + 1] = excl + d0;
    if (base + 2 < n) out[base + 2] = excl + d0 + d1;
    if (base + 3 < n) out[base + 3] = excl + d0 + d1 + d2;
}

// ---------------- partition: scatter to bins ----------------

__global__ void k_pass2(const int* __restrict__ src, const int* __restrict__ dst,
                        const int* __restrict__ hist_scan, int* __restrict__ recs) {
    __shared__ int curs[NBINS];
    if (threadIdx.x < NBINS) curs[threadIdx.x] = hist_scan[threadIdx.x * PB + blockIdx.x];
    __syncthreads();
    int base = blockIdx.x * EPB;
    for (int i = threadIdx.x; i < EPB; i += 256) {
        int e = base + i;
        int s = src[e], d = dst[e];
        int pos = atomicAdd(&curs[d >> 9], 1);
        recs[pos] = s | ((d & 511) << 17);            // src:17b | dst_local:9b
    }
}

// ---------------- fused per-bin: degree + dinv + row_start + CSR scatter ----------------

__global__ void k_degsort(const int* __restrict__ recs, const int* __restrict__ hist_scan,
                          int* __restrict__ deg, float* __restrict__ dinv,
                          int* __restrict__ row_start, int* __restrict__ csr) {
    __shared__ int cnt[BINW];
    __shared__ int scn[BINW];
    int bin = blockIdx.x, t = threadIdx.x;
    cnt[t] = 0;
    __syncthreads();
    int s0 = hist_scan[bin * PB];
    int s1 = (bin + 1 < NBINS) ? hist_scan[(bin + 1) * PB] : NE;
    for (int r = s0 + t; r < s1; r += BINW)
        atomicAdd(&cnt[((unsigned)recs[r]) >> 17], 1);
    __syncthreads();
    scn[t] = cnt[t];
    __syncthreads();
    for (int off = 1; off < BINW; off <<= 1) {
        int v = (t >= off) ? scn[t - off] : 0;
        __syncthreads();
        scn[t] += v;
        __syncthreads();
    }
    int node = bin * BINW + t;
    int rs = s0 + scn[t] - cnt[t];
    if (node < NN) {
        int c = cnt[t];
        deg[node]       = c;
        dinv[node]      = (c > 0) ? rsqrtf((float)c) : 0.f;
        row_start[node] = rs;
    }
    scn[t] = rs;
    __syncthreads();
    for (int r = s0 + t; r < s1; r += BINW) {
        int rec = recs[r];
        int pos = atomicAdd(&scn[((unsigned)rec) >> 17], 1);
        csr[pos] = rec & 0x1FFFF;
    }
}

// ---------------- layer 1 dense transform: register-tiled GEMM ----------------
// block: 128 nodes x 96 outputs (48 A-cols + 48 R-cols); thread: 4 nodes x 12 outputs.

__global__ void k_transform1(const float* __restrict__ x, const float* __restrict__ iw,
                             const float* __restrict__ rw, const float* __restrict__ b1,
                             const float* __restrict__ dinv,
                             __half* __restrict__ A, __half* __restrict__ Bpad,
                             float* __restrict__ R) {
    if (blockIdx.x == TNB) {   // zero the pad rows (index NN) of A and B
        int t = threadIdx.x;
        if (t < PAD) A[(size_t)NN * PAD + t] = __float2half(0.f);
        else if (t < 2 * PAD) Bpad[(size_t)NN * PAD + (t - PAD)] = __float2half(0.f);
        return;
    }
    __shared__ float xs[FEA * XS_STRIDE];     // xT[f][n_local], 35376 B
    __shared__ float wTs[96 * WT_STRIDE];     // wT[j][f], 26112 B (j<48: iw, j>=48: rw)
    __shared__ float bb[KH];
    int n0g = blockIdx.x * TBM;

    // stage weights transposed
    for (int idx = threadIdx.x; idx < 96 * FEA; idx += 256) {
        int j = idx / FEA, f = idx % FEA;
        float v;
        if (j < KH) v = iw[(j >> 4) * (FEA * HID) + f * HID + (j & 15)];
        else { int jr = j - KH; v = rw[(jr >> 4) * (FEA * HID) + f * HID + (jr & 15)]; }
        wTs[j * WT_STRIDE + f] = v;
    }
    if (threadIdx.x < KH) bb[threadIdx.x] = b1[threadIdx.x];
    // stage x tile transposed (coalesced global reads)
    for (int idx = threadIdx.x; idx < TBM * FEA; idx += 256) {
        int nl = idx / FEA, f = idx % FEA;
        int n = n0g + nl;
        xs[f * XS_STRIDE + nl] = (n < NN) ? x[(size_t)n * FEA + f] : 0.f;
    }
    __syncthreads();

    int tx = threadIdx.x & 31, ty = threadIdx.x >> 5;   // 32 x 8
    int nl0 = tx * 4;
    int j0  = ty * 12;
    float acc[4][12];
    #pragma unroll
    for (int p = 0; p < 12; ++p) {
        float init = (j0 >= KH) ? bb[j0 - KH + p] : 0.f;
        acc[0][p] = init; acc[1][p] = init; acc[2][p] = init; acc[3][p] = init;
    }

    #pragma unroll 4
    for (int fb = 0; fb < 16; ++fb) {
        int f0 = fb * 4;
        float4 xv0 = *(const float4*)&xs[(f0 + 0) * XS_STRIDE + nl0];
        float4 xv1 = *(const float4*)&xs[(f0 + 1) * XS_STRIDE + nl0];
        float4 xv2 = *(const float4*)&xs[(f0 + 2) * XS_STRIDE + nl0];
        float4 xv3 = *(const float4*)&xs[(f0 + 3) * XS_STRIDE + nl0];
        #pragma unroll
        for (int p = 0; p < 12; ++p) {
            float4 wv = *(const float4*)&wTs[(j0 + p) * WT_STRIDE + f0];
            acc[0][p] += xv0.x * wv.x + xv1.x * wv.y + xv2.x * wv.z + xv3.x * wv.w;
            acc[1][p] += xv0.y * wv.x + xv1.y * wv.y + xv2.y * wv.z + xv3.y * wv.w;
            acc[2][p] += xv0.z * wv.x + xv1.z * wv.y + xv2.z * wv.z + xv3.z * wv.w;
            acc[3][p] += xv0.w * wv.x + xv1.w * wv.y + xv2.w * wv.z + xv3.w * wv.w;
        }
    }
    #pragma unroll
    for (int f = 64; f < FEA; ++f) {
        float x0 = xs[f * XS_STRIDE + nl0 + 0];
        float x1 = xs[f * XS_STRIDE + nl0 + 1];
        float x2 = xs[f * XS_STRIDE + nl0 + 2];
        float x3 = xs[f * XS_STRIDE + nl0 + 3];
        #pragma unroll
        for (int p = 0; p < 12; ++p) {
            float wv = wTs[(j0 + p) * WT_STRIDE + f];
            acc[0][p] += x0 * wv; acc[1][p] += x1 * wv;
            acc[2][p] += x2 * wv; acc[3][p] += x3 * wv;
        }
    }

    if (j0 < KH) {   // A outputs: scale by dinv, fp16 pairs
        #pragma unroll
        for (int nq = 0; nq < 4; ++nq) {
            int n = n0g + nl0 + nq;
            if (n < NN) {
                float dv = dinv[n];
                __half2* Ap = (__half2*)A + (size_t)n * (PAD / 2) + (j0 >> 1);
                #pragma unroll
                for (int p2 = 0; p2 < 6; ++p2)
                    Ap[p2] = __halves2half2(__float2half_rn(acc[nq][2 * p2] * dv),
                                            __float2half_rn(acc[nq][2 * p2 + 1] * dv));
            }
        }
    } else {         // R outputs: bias already in acc, float4 stores
        int jr = j0 - KH;
        #pragma unroll
        for (int nq = 0; nq < 4; ++nq) {
            int n = n0g + nl0 + nq;
            if (n < NN) {
                float* Rp = &R[(size_t)n * KH + jr];
                *(float4*)(Rp + 0) = make_float4(acc[nq][0], acc[nq][1], acc[nq][2],  acc[nq][3]);
                *(float4*)(Rp + 4) = make_float4(acc[nq][4], acc[nq][5], acc[nq][6],  acc[nq][7]);
                *(float4*)(Rp + 8) = make_float4(acc[nq][8], acc[nq][9], acc[nq][10], acc[nq][11]);
            }
        }
    }
}

// ---------------- SpMM 48-wide: pair scheme (2 edges/wave-iter, half2 gathers) ----------------

template <bool FUSEW>
__global__ void k_spmm48(const __half2* __restrict__ Asrc,   // row stride PAD/2 half2
                         const float* __restrict__ R,
                         const int* __restrict__ row_start, const int* __restrict__ deg,
                         const float* __restrict__ dinv, const int* __restrict__ csr,
                         const float* __restrict__ w1, __half2* __restrict__ Bout) {
    __shared__ float w1s[FUSEW ? KS * HID * HID : 1];
    if (FUSEW) {
        for (int i = threadIdx.x; i < KS * HID * HID; i += 256) w1s[i] = w1[i];
        __syncthreads();
    }
    int node = (blockIdx.x * 256 + threadIdx.x) >> 6;   // one wave per node
    int lane = threadIdx.x & 63;
    int eo   = lane >> 5;           // edge parity within pair
    int cl   = lane & 31;           // col-pair index (cols 2cl, 2cl+1)
    int start = __builtin_amdgcn_readfirstlane(row_start[node]);
    int d     = __builtin_amdgcn_readfirstlane(deg[node]);
    float dv  = dinv[node];
    float ax = 0.f, ay = 0.f;
    for (int b = 0; b < d; b += 64) {
        int nb  = min(64, d - b);
        int myc = csr[start + b + lane];    // one coalesced load per 64-edge chunk
        int npf = nb >> 1;                  // full pairs
        int p = 0;
        for (; p + 4 <= npf; p += 4) {
            int c0 = __shfl(myc, 2 * (p + 0) + eo, 64);
            int c1 = __shfl(myc, 2 * (p + 1) + eo, 64);
            int c2 = __shfl(myc, 2 * (p + 2) + eo, 64);
            int c3 = __shfl(myc, 2 * (p + 3) + eo, 64);
            float2 f0 = __half22float2(Asrc[(size_t)c0 * (PAD / 2) + cl]);
            float2 f1 = __half22float2(Asrc[(size_t)c1 * (PAD / 2) + cl]);
            float2 f2 = __half22float2(Asrc[(size_t)c2 * (PAD / 2) + cl]);
            float2 f3 = __half22float2(Asrc[(size_t)c3 * (PAD / 2) + cl]);
            ax += f0.x + f1.x; ay += f0.y + f1.y;
            ax += f2.x + f3.x; ay += f2.y + f3.y;
        }
        for (; p < npf; ++p) {
            int c = __shfl(myc, 2 * p + eo, 64);
            float2 f = __half22float2(Asrc[(size_t)c * (PAD / 2) + cl]);
            ax += f.x; ay += f.y;
        }
        if (nb & 1) {                        // odd tail: only parity-0 edge exists
            int c = __shfl(myc, nb - 1, 64);
            c = (eo == 0) ? c : NN;          // parity-1 lanes add the zeroed pad row
            float2 f = __half22float2(Asrc[(size_t)c * (PAD / 2) + cl]);
            ax += f.x; ay += f.y;
        }
    }
    // combine edge parities
    ax += __shfl_xor(ax, 32, 64);
    ay += __shfl_xor(ay, 32, 64);
    // root + relu (both layer-1 propagates end in relu)
    float2 r2 = make_float2(0.f, 0.f);
    if (cl < 24) r2 = *(const float2*)&R[(size_t)node * KH + 2 * cl];
    float vx = fmaxf(ax * dv + r2.x, 0.f);
    float vy = fmaxf(ay * dv + r2.y, 0.f);
    if (FUSEW) {
        // out[k*16+p0], out[k*16+p0+1] = sum_h in[k*16+h] * w1[k][h][p]
        int k  = cl >> 3;              // (2cl)>>4
        int p0 = (2 * cl) & 15;
        float o0 = 0.f, o1 = 0.f;
        #pragma unroll
        for (int h2 = 0; h2 < 8; ++h2) {
            float ix = __shfl(vx, k * 8 + h2, 64);   // in[k*16 + 2h2]
            float iy = __shfl(vy, k * 8 + h2, 64);   // in[k*16 + 2h2+1]
            o0 += ix * w1s[k * 256 + (2 * h2) * 16 + p0]     + iy * w1s[k * 256 + (2 * h2 + 1) * 16 + p0];
            o1 += ix * w1s[k * 256 + (2 * h2) * 16 + p0 + 1] + iy * w1s[k * 256 + (2 * h2 + 1) * 16 + p0 + 1];
        }
        if (eo == 0 && cl < 24)
            Bout[(size_t)node * (PAD / 2) + cl] =
                __halves2half2(__float2half_rn(o0 * dv), __float2half_rn(o1 * dv));
    } else {
        if (eo == 0 && cl < 24)
            Bout[(size_t)node * (PAD / 2) + cl] =
                __halves2half2(__float2half_rn(vx), __float2half_rn(vy));
    }
}

// ---------------- fused mean+relu+transform2 (reads fp16 padded L1; A2 pre-scaled) ----------------

__global__ void k_mt2(const __half* __restrict__ L1, const float* __restrict__ iw,
                      const float* __restrict__ rw, const float* __restrict__ b2,
                      const float* __restrict__ dinv,
                      float* __restrict__ A2, float* __restrict__ R2) {
    __shared__ float wi[KS * HID * OUTC];
    __shared__ float wr_[KS * HID * OUTC];
    __shared__ float bb[KO];
    if (threadIdx.x < KS * HID * OUTC) { wi[threadIdx.x] = iw[threadIdx.x]; wr_[threadIdx.x] = rw[threadIdx.x]; }
    if (threadIdx.x < KO) bb[threadIdx.x] = b2[threadIdx.x];
    __syncthreads();
    int n = blockIdx.x * 256 + threadIdx.x;
    if (n >= NN) return;
    const __half2* hp = (const __half2*)(L1 + (size_t)n * PAD);
    float v[KH];
    #pragma unroll
    for (int q = 0; q < 24; ++q) {
        float2 f = __half22float2(hp[q]);
        v[q * 2 + 0] = f.x; v[q * 2 + 1] = f.y;
    }
    float h[HID];
    #pragma unroll
    for (int hh = 0; hh < HID; ++hh)
        h[hh] = fmaxf((v[hh] + v[16 + hh] + v[32 + hh]) * (1.f / 3.f), 0.f);
    float dv = dinv[n];
    #pragma unroll
    for (int k = 0; k < KS; ++k) {
        #pragma unroll
        for (int o = 0; o < OUTC; ++o) {
            float a = 0.f, r = bb[k * 2 + o];
            #pragma unroll
            for (int hh = 0; hh < HID; ++hh) {
                a += h[hh] * wi[k * 32 + hh * 2 + o];
                r += h[hh] * wr_[k * 32 + hh * 2 + o];
            }
            A2[n * KO + k * 2 + o] = a * dv;
            R2[n * KO + k * 2 + o] = r;
        }
    }
}

// ---------------- SpMM 6-wide #1: fused 2x2 gemm (w2), output pre-scaled ----------------

__global__ void k_spmm6_g(const float* __restrict__ Asrc, const float* __restrict__ R2,
                          const int* __restrict__ row_start, const int* __restrict__ deg,
                          const float* __restrict__ dinv, const int* __restrict__ csr,
                          const float* __restrict__ w2, float* __restrict__ Bout) {
    __shared__ float ws[KS * OUTC * OUTC];
    if (threadIdx.x < KS * OUTC * OUTC) ws[threadIdx.x] = w2[threadIdx.x];
    __syncthreads();
    int t = blockIdx.x * 256 + threadIdx.x;
    int node = t / KO, j = t % KO;
    bool active = node < NN;
    float acc = 0.f, r = 0.f, dv = 0.f;
    int start = 0, d = 0;
    if (active) {
        start = row_start[node];
        d     = deg[node];
        r     = R2[node * KO + j];
        dv    = dinv[node];
    }
    int e = 0;
    for (; e + 4 <= d; e += 4) {
        int c0 = csr[start + e + 0];
        int c1 = csr[start + e + 1];
        int c2 = csr[start + e + 2];
        int c3 = csr[start + e + 3];
        acc += Asrc[c0 * KO + j];
        acc += Asrc[c1 * KO + j];
        acc += Asrc[c2 * KO + j];
        acc += Asrc[c3 * KO + j];
    }
    for (; e < d; ++e)
        acc += Asrc[csr[start + e] * KO + j];
    float v = acc * dv + r;
    float other = __shfl_xor(v, 1, 64);
    if (active) {
        int k = j >> 1, p = j & 1;
        float v0 = (p == 0) ? v : other;
        float v1 = (p == 0) ? other : v;
        Bout[node * KO + j] = (v0 * ws[k * 4 + p] + v1 * ws[k * 4 + 2 + p]) * dv;
    }
}

// ---------------- SpMM 6-wide #2: fused mean + log_softmax (10 nodes/wave) ----------------

__global__ void k_spmm6_f(const float* __restrict__ Asrc, const float* __restrict__ R2,
                          const int* __restrict__ row_start, const int* __restrict__ deg,
                          const float* __restrict__ dinv, const int* __restrict__ csr,
                          float* __restrict__ out) {
    int wave = threadIdx.x >> 6;
    int l    = threadIdx.x & 63;
    int nl   = l / 6;            // 0..10 (10 = inactive)
    int j    = l - nl * 6;
    bool active = nl < 10;
    int node = blockIdx.x * 40 + wave * 10 + nl;
    float acc = 0.f, r = 0.f, dv = 0.f;
    int start = 0, d = 0;
    if (active) {
        start = row_start[node];
        d     = deg[node];
        r     = R2[node * KO + j];
        dv    = dinv[node];
    }
    int e = 0;
    for (; e + 4 <= d; e += 4) {
        int c0 = csr[start + e + 0];
        int c1 = csr[start + e + 1];
        int c2 = csr[start + e + 2];
        int c3 = csr[start + e + 3];
        acc += Asrc[c0 * KO + j];
        acc += Asrc[c1 * KO + j];
        acc += Asrc[c2 * KO + j];
        acc += Asrc[c3 * KO + j];
    }
    for (; e < d; ++e)
        acc += Asrc[csr[start + e] * KO + j];
    float v = acc * dv + r;
    int base = nl * 6;
    float o0 = (__shfl(v, base + 0, 64) + __shfl(v, base + 2, 64) + __shfl(v, base + 4, 64)) * (1.f / 3.f);
    float o1 = (__shfl(v, base + 1, 64) + __shfl(v, base + 3, 64) + __shfl(v, base + 5, 64)) * (1.f / 3.f);
    if (active && j == 0) {
        float m = fmaxf(o0, o1);
        float ls = m + logf(expf(o0 - m) + expf(o1 - m));
        *(float2*)(out + (size_t)node * 2) = make_float2(o0 - ls, o1 - ls);
    }
}

// ---------------- host ----------------

extern "C" void kernel_launch(void* const* d_in, const int* in_sizes, int n_in,
                              void* d_out, int out_size, void* d_ws, size_t ws_size,
                              hipStream_t stream) {
    const float* x   = (const float*)d_in[0];
    const int*   ei  = (const int*)d_in[1];
    const float* iw1 = (const float*)d_in[2];
    const float* w1  = (const float*)d_in[3];
    const float* rw1 = (const float*)d_in[4];
    const float* b1  = (const float*)d_in[5];
    const float* iw2 = (const float*)d_in[6];
    const float* w2  = (const float*)d_in[7];
    const float* rw2 = (const float*)d_in[8];
    const float* b2  = (const float*)d_in[9];
    const int* src = ei;
    const int* dst = ei + NE;
    float* out = (float*)d_out;

    char* ws = (char*)d_ws;
    size_t o = 0;
    int*    deg       = (int*)(ws + o);    o += (size_t)NN * 4;
    int*    row_start = (int*)(ws + o);    o += (size_t)NN * 4;
    float*  dinv      = (float*)(ws + o);  o += (size_t)NN * 4;
    int*    hist      = (int*)(ws + o);    o += (size_t)M1 * 4;
    int*    hist_scan = (int*)(ws + o);    o += (size_t)M1 * 4;
    int*    partials  = (int*)(ws + o);    o += 128 * 4;
    int*    csr       = (int*)(ws + o);    o += (size_t)(NE + 64) * 4;       // +64 chunk-read slack
    __half* A         = (__half*)(ws + o); o += (size_t)(NN + 1) * PAD * 2;  // 12.8MB (padded rows + zero row)
    float*  R         = (float*)(ws + o);  o += (size_t)NN * KH * 4;         // 19.2MB
    __half* B         = (__half*)(ws + o); o += (size_t)(NN + 1) * PAD * 2;  // 12.8MB
    // overlays
    int*    recs  = (int*)A;                 // NE*4 = 12.8MB fits in A region; dead before transform1
    __half* L1f   = A;                       // spmm48#2 output (reads B, not A)
    float*  A2    = R;                       // layer-2 buffers live in R (dead after spmm48#2)
    float*  R2    = R + (size_t)NN * KO;
    float*  C2    = R + (size_t)NN * KO * 2;

    // ---- CSR build (5 dispatches) ----
    k_hist       <<<PB, 256, 0, stream>>>(dst, hist);
    k_partial    <<<NSCB, 256, 0, stream>>>(hist, partials, M1);
    k_downsweepF <<<NSCB, 256, 0, stream>>>(hist, partials, hist_scan, M1);
    k_pass2      <<<PB, 256, 0, stream>>>(src, dst, hist_scan, recs);
    k_degsort    <<<NBINS, BINW, 0, stream>>>(recs, hist_scan, deg, dinv, row_start, csr);

    // ---- layer 1 ----
    k_transform1    <<<TNB + 1, 256, 0, stream>>>(x, iw1, rw1, b1, dinv, A, B, R);
    k_spmm48<true>  <<<NN / 4, 256, 0, stream>>>((const __half2*)A, R, row_start, deg, dinv, csr, w1, (__half2*)B);
    k_spmm48<false> <<<NN / 4, 256, 0, stream>>>((const __half2*)B, R, row_start, deg, dinv, csr, w1, (__half2*)L1f);

    // ---- layer 2 ----
    k_mt2      <<<(NN + 255) / 256, 256, 0, stream>>>(L1f, iw2, rw2, b2, dinv, A2, R2);
    k_spmm6_g  <<<(NN * KO + 255) / 256, 256, 0, stream>>>(A2, R2, row_start, deg, dinv, csr, w2, C2);
    k_spmm6_f  <<<NN / 40, 256, 0, stream>>>(C2, R2, row_start, deg, dinv, csr, out);
}